// Round 1
// baseline (377.311 us; speedup 1.0000x reference)
//
#include <hip/hip_runtime.h>

typedef unsigned short u16;
typedef __attribute__((ext_vector_type(8))) short bf16x8;
typedef __attribute__((ext_vector_type(4))) float f32x4;

#define LOG2E 1.44269504088896340736f

__device__ inline u16 f2b(float f) {
    unsigned int u = __builtin_bit_cast(unsigned int, f);
    unsigned int r = u + 0x7fffu + ((u >> 16) & 1u);
    return (u16)(r >> 16);
}
__device__ inline float b2f(u16 h) {
    unsigned int u = ((unsigned int)h) << 16;
    return __builtin_bit_cast(float, u);
}

#define GLOAD_LDS16(g, l) \
    __builtin_amdgcn_global_load_lds( \
        (const __attribute__((address_space(1))) unsigned int*)(g), \
        (__attribute__((address_space(3))) unsigned int*)(l), 16, 0, 0)

// ---------------- fused cast fp32 -> bf16 for all 5 inputs, 8 elems/thread ----
// element boundaries: x 8388608 | wq 4194304 | wk 1048576 | wv 1048576 | wo 4194304
// wqkvb [3072 x 2048]: Q rows off 0, K rows off 4194304, V rows off 5242880.
__global__ __launch_bounds__(256) void cast_all(
    const float* __restrict__ x, const float* __restrict__ wq,
    const float* __restrict__ wk, const float* __restrict__ wv,
    const float* __restrict__ wo, u16* __restrict__ xb,
    u16* __restrict__ wqkvb, u16* __restrict__ wob) {
    long i = ((long)blockIdx.x * 256 + threadIdx.x) * 8;
    const float* s;
    u16* d;
    if (i < 8388608)       { s = x  + i;              d = xb + i; }
    else if (i < 12582912) { s = wq + (i - 8388608);  d = wqkvb + (i - 8388608); }
    else if (i < 13631488) { s = wk + (i - 12582912); d = wqkvb + 4194304 + (i - 12582912); }
    else if (i < 14680064) { s = wv + (i - 13631488); d = wqkvb + 5242880 + (i - 13631488); }
    else                   { s = wo + (i - 14680064); d = wob + (i - 14680064); }
    float4 v0 = *(const float4*)s;
    float4 v1 = *(const float4*)(s + 4);
    ushort4 o0 = make_ushort4(f2b(v0.x), f2b(v0.y), f2b(v0.z), f2b(v0.w));
    ushort4 o1 = make_ushort4(f2b(v1.x), f2b(v1.y), f2b(v1.z), f2b(v1.w));
    *(ushort4*)d = o0;
    *(ushort4*)(d + 4) = o1;
}

// ---------------- fused RoPE (Q+K) and V-transpose in one launch ----------------
// blocks [0,5120): rope, 8 elems/thread. blocks [5120,5632): vtrans 64x64 tile.
__global__ __launch_bounds__(256) void rope_vtrans(
    u16* __restrict__ qkv, u16* __restrict__ VT, float qscale) {
    const int S = 2048, RS = 3072;
    int tid = threadIdx.x;
    if (blockIdx.x < 5120) {
        int idx = blockIdx.x * 256 + tid;   // < 4096*320
        int row = idx / 320;
        int rem = idx - row * 320;
        int head = rem >> 3, chunk = rem & 7;
        int pos = row & 2047;
        int coloff;
        float scale;
        if (head < 32) { coloff = head * 64;               scale = qscale; }
        else           { coloff = 2048 + (head - 32) * 64; scale = 1.0f; }
        u16* p = qkv + (size_t)row * RS + coloff + chunk * 8;
        bf16x8 v = *(bf16x8*)p;
        float t0 = exp2f((float)(chunk * 4) * -0.41524101186092f);
        const float tc[4] = {1.0f, 0.74989420933246f, 0.56234132519035f, 0.42169650342858f};
        float fpos = (float)pos;
        #pragma unroll
        for (int i = 0; i < 4; i++) {
            float f = fpos * (t0 * tc[i]);
            float rev = f * 0.15915494309189535f;  // radians -> revolutions
            rev = rev - floorf(rev);
            float sn = __builtin_amdgcn_sinf(rev);
            float cs = __builtin_amdgcn_cosf(rev);
            float e0 = b2f((u16)v[2 * i]), e1 = b2f((u16)v[2 * i + 1]);
            v[2 * i]     = (short)f2b((e0 * cs - e1 * sn) * scale);
            v[2 * i + 1] = (short)f2b((e1 * cs + e0 * sn) * scale);
        }
        *(bf16x8*)p = v;
    } else {
        int bid = blockIdx.x - 5120;        // 0..511
        int st = bid & 31, g = (bid >> 5) & 7, b = bid >> 8;
        __shared__ u16 T[64 * 72];
        for (int c = tid; c < 512; c += 256) {
            int sr = c >> 3, dc = (c & 7) * 8;
            *(bf16x8*)&T[sr * 72 + dc] =
                *(const bf16x8*)(qkv + ((size_t)b * S + st * 64 + sr) * RS + 2560 + g * 64 + dc);
        }
        __syncthreads();
        for (int c = tid; c < 512; c += 256) {
            int d = c >> 3, sc = (c & 7) * 8;
            bf16x8 o;
            #pragma unroll
            for (int j = 0; j < 8; j++) o[j] = (short)T[(sc + j) * 72 + d];
            *(bf16x8*)(VT + ((size_t)((b * 8 + g) * 64 + d)) * S + st * 64 + sc) = o;
        }
    }
}

// ---------------- GEMM m97-style: C[M,N] = A[M,K]*B[N,K]^T ----------------
__global__ __launch_bounds__(256) void gemm_bt128(
    const u16* __restrict__ A, const u16* __restrict__ B, void* __restrict__ Cv,
    int M, int N, int K, int c_is_f32) {
    __shared__ u16 As[128 * 32];
    __shared__ u16 Bs[128 * 32];
    const int tid = threadIdx.x;
    const int lane = tid & 63, wave = tid >> 6;
    const int ln = lane & 15, quad = lane >> 4;
    const int wm = wave >> 1, wn = wave & 1;
    const int m0 = blockIdx.y * 128, n0 = blockIdx.x * 128;

    const int srow = wave * 16 + (lane >> 2);
    const int skc = (lane & 3) * 8;
    const u16* Ag = A + (size_t)(m0 + srow) * K + skc;
    const u16* Bg = B + (size_t)(n0 + srow) * K + skc;

    f32x4 acc[4][4] = {};
    for (int k0 = 0; k0 < K; k0 += 32) {
        #pragma unroll
        for (int t = 0; t < 2; t++) {
            GLOAD_LDS16(Ag + (size_t)t * 64 * K + k0, As + t * 2048 + wave * 512);
            GLOAD_LDS16(Bg + (size_t)t * 64 * K + k0, Bs + t * 2048 + wave * 512);
        }
        __syncthreads();

        bf16x8 af[4], bfr[4];
        #pragma unroll
        for (int i = 0; i < 4; i++) {
            af[i]  = *(const bf16x8*)&As[(wm * 64 + i * 16 + ln) * 32 + quad * 8];
            bfr[i] = *(const bf16x8*)&Bs[(wn * 64 + i * 16 + ln) * 32 + quad * 8];
        }
        #pragma unroll
        for (int mi = 0; mi < 4; mi++)
            #pragma unroll
            for (int nt = 0; nt < 4; nt++)
                acc[mi][nt] = __builtin_amdgcn_mfma_f32_16x16x32_bf16(
                    af[mi], bfr[nt], acc[mi][nt], 0, 0, 0);
        __syncthreads();
    }

    #pragma unroll
    for (int mi = 0; mi < 4; mi++)
        #pragma unroll
        for (int nt = 0; nt < 4; nt++)
            #pragma unroll
            for (int r = 0; r < 4; r++) {
                int row = m0 + wm * 64 + mi * 16 + quad * 4 + r;
                int col = n0 + wn * 64 + nt * 16 + ln;
                float v = acc[mi][nt][r];
                if (c_is_f32) ((float*)Cv)[(size_t)row * N + col] = v;
                else          ((u16*)Cv)[(size_t)row * N + col] = f2b(v);
            }
}

// ---------------- Flash attention, GQA, causal, fused paired q-tiles ---------
// grid: (S/128, H, B). Q pre-scaled by (1/8)*log2e in RoPE. No online max.
// ROUND-0 CHANGE: V fragments are read directly from global VT (L1/L2-resident,
// 256 KB per (b,g) slab) instead of being staged through LDS. Model: attn was
// LDS-BW-bound (~96 KB LDS traffic per body per CU vs ~90cy MFMA wall); dropping
// the V stage+read removes ~40 KB/CU-body of LDS traffic. All 4 waves read
// identical V addresses -> L1 absorbs the redundancy. Also: s_setprio(1) around
// both MFMA clusters (T5, measured +4-7% on attn-shaped kernels).
__global__ __launch_bounds__(256) void attn_kernel(
    const u16* __restrict__ QKV, const u16* __restrict__ VT, u16* __restrict__ O) {
    const int S = 2048, RS = 3072, DO = 2048;
    const int b = blockIdx.z, h = blockIdx.y, p = blockIdx.x;
    const int g = h >> 2;
    const int qtl = p, qth = (S / 64 - 1) - p;   // qtl <= 15 < 16 <= qth
    const int tid = threadIdx.x;
    const int lane = tid & 63, wave = tid >> 6;
    const int ln = lane & 15, quad = lane >> 4;

    __shared__ u16 Ks[64 * 72];
    __shared__ u16 Psh[64 * 68];
    __shared__ u16 Psl[64 * 68];

    const u16* Qb = QKV + (size_t)b * S * RS + h * 64 + quad * 8;
    bf16x8 aqh0 = *(const bf16x8*)(Qb + (size_t)(qth * 64 + wave * 16 + ln) * RS);
    bf16x8 aqh1 = *(const bf16x8*)(Qb + (size_t)(qth * 64 + wave * 16 + ln) * RS + 32);
    bf16x8 aql0 = *(const bf16x8*)(Qb + (size_t)(qtl * 64 + wave * 16 + ln) * RS);
    bf16x8 aql1 = *(const bf16x8*)(Qb + (size_t)(qtl * 64 + wave * 16 + ln) * RS + 32);

    const u16* Kb = QKV + (size_t)b * S * RS + 2048 + g * 64;
    const u16* VTb = VT + (size_t)(b * 8 + g) * 64 * S;

    const bf16x8 vones = {0x3F80, 0x3F80, 0x3F80, 0x3F80, 0x3F80, 0x3F80, 0x3F80, 0x3F80};

    f32x4 acch[5] = {}, accl[5] = {};  // [0..3]=O tiles, [4]=row-sum l

    const int r0 = tid >> 3;            // 0..31
    const int dc0 = (tid & 7) * 8;
    bf16x8 kreg0, kreg1;
    auto loadK = [&](int kt) {
        kreg0 = *(const bf16x8*)(Kb + (size_t)(kt * 64 + r0) * RS + dc0);
        kreg1 = *(const bf16x8*)(Kb + (size_t)(kt * 64 + r0 + 32) * RS + dc0);
    };

    // body: DUAL/MH/ML are compile-time constants at every call site.
    auto body = [&](int kt, bool DUAL, bool MH, bool ML) {
        __syncthreads();  // protect Ks from previous iteration's readers
        *(bf16x8*)&Ks[r0 * 72 + dc0] = kreg0;
        *(bf16x8*)&Ks[(r0 + 32) * 72 + dc0] = kreg1;
        __syncthreads();
        if (kt < qth) loadK(kt + 1);  // prefetch overlaps compute

        // V fragments for THIS tile straight from global (L1/L2 hit);
        // issued before the QK^T phase so latency hides under the MFMAs.
        bf16x8 vr[2][4];
        #pragma unroll
        for (int kk = 0; kk < 2; kk++)
            #pragma unroll
            for (int nt = 0; nt < 4; nt++)
                vr[kk][nt] = *(const bf16x8*)(VTb + (size_t)(nt * 16 + ln) * S
                                              + kt * 64 + kk * 32 + quad * 8);

        f32x4 sh[4] = {}, sl[4] = {};
        __builtin_amdgcn_s_setprio(1);
        #pragma unroll
        for (int nt = 0; nt < 4; nt++) {
            bf16x8 bk0 = *(const bf16x8*)&Ks[(nt * 16 + ln) * 72 + quad * 8];
            bf16x8 bk1 = *(const bf16x8*)&Ks[(nt * 16 + ln) * 72 + 32 + quad * 8];
            sh[nt] = __builtin_amdgcn_mfma_f32_16x16x32_bf16(aqh0, bk0, sh[nt], 0, 0, 0);
            sh[nt] = __builtin_amdgcn_mfma_f32_16x16x32_bf16(aqh1, bk1, sh[nt], 0, 0, 0);
            if (DUAL) {
                sl[nt] = __builtin_amdgcn_mfma_f32_16x16x32_bf16(aql0, bk0, sl[nt], 0, 0, 0);
                sl[nt] = __builtin_amdgcn_mfma_f32_16x16x32_bf16(aql1, bk1, sl[nt], 0, 0, 0);
            }
        }
        __builtin_amdgcn_s_setprio(0);

        if (MH) {
            #pragma unroll
            for (int nt = 0; nt < 4; nt++)
                #pragma unroll
                for (int r = 0; r < 4; r++)
                    if (nt * 16 + ln > wave * 16 + quad * 4 + r) sh[nt][r] = -INFINITY;
        }
        #pragma unroll
        for (int nt = 0; nt < 4; nt++)
            #pragma unroll
            for (int r = 0; r < 4; r++) {
                float pv = exp2f(sh[nt][r]);
                Psh[(wave * 16 + quad * 4 + r) * 68 + nt * 16 + ln] =
                    (u16)(__builtin_bit_cast(unsigned int, pv) >> 16);
            }
        if (DUAL) {
            if (ML) {
                #pragma unroll
                for (int nt = 0; nt < 4; nt++)
                    #pragma unroll
                    for (int r = 0; r < 4; r++)
                        if (nt * 16 + ln > wave * 16 + quad * 4 + r) sl[nt][r] = -INFINITY;
            }
            #pragma unroll
            for (int nt = 0; nt < 4; nt++)
                #pragma unroll
                for (int r = 0; r < 4; r++) {
                    float pv = exp2f(sl[nt][r]);
                    Psl[(wave * 16 + quad * 4 + r) * 68 + nt * 16 + ln] =
                        (u16)(__builtin_bit_cast(unsigned int, pv) >> 16);
                }
        }
        // no barrier: Ps rows are wave-private (same-wave LDS ordering)

        __builtin_amdgcn_s_setprio(1);
        #pragma unroll
        for (int kk = 0; kk < 2; kk++) {
            bf16x8 aph = *(const bf16x8*)&Psh[(wave * 16 + ln) * 68 + kk * 32 + quad * 8];
            #pragma unroll
            for (int nt = 0; nt < 4; nt++)
                acch[nt] = __builtin_amdgcn_mfma_f32_16x16x32_bf16(aph, vr[kk][nt], acch[nt], 0, 0, 0);
            acch[4] = __builtin_amdgcn_mfma_f32_16x16x32_bf16(aph, vones, acch[4], 0, 0, 0);
            if (DUAL) {
                bf16x8 apl = *(const bf16x8*)&Psl[(wave * 16 + ln) * 68 + kk * 32 + quad * 8];
                #pragma unroll
                for (int nt = 0; nt < 4; nt++)
                    accl[nt] = __builtin_amdgcn_mfma_f32_16x16x32_bf16(apl, vr[kk][nt], accl[nt], 0, 0, 0);
                accl[4] = __builtin_amdgcn_mfma_f32_16x16x32_bf16(apl, vones, accl[4], 0, 0, 0);
            }
        }
        __builtin_amdgcn_s_setprio(0);
    };

    loadK(0);
    for (int kt = 0; kt < qtl; kt++) body(kt, true, false, false);   // dual, unmasked
    body(qtl, true, false, true);                                    // dual, qtl diagonal
    for (int kt = qtl + 1; kt < qth; kt++) body(kt, false, false, false); // single
    body(qth, false, true, false);                                   // single, qth diagonal

    // epilogue
    u16* Ob = O + (size_t)b * S * DO + h * 64;
    #pragma unroll
    for (int r = 0; r < 4; r++) {
        float invh = 1.0f / acch[4][r];
        float invl = 1.0f / accl[4][r];
        int qh = qth * 64 + wave * 16 + quad * 4 + r;
        int ql = qtl * 64 + wave * 16 + quad * 4 + r;
        #pragma unroll
        for (int nt = 0; nt < 4; nt++) {
            Ob[(size_t)qh * DO + nt * 16 + ln] = f2b(acch[nt][r] * invh);
            Ob[(size_t)ql * DO + nt * 16 + ln] = f2b(accl[nt][r] * invl);
        }
    }
}

extern "C" void kernel_launch(void* const* d_in, const int* in_sizes, int n_in,
                              void* d_out, int out_size, void* d_ws, size_t ws_size,
                              hipStream_t stream) {
    const float* x  = (const float*)d_in[0];
    const float* wq = (const float*)d_in[1];
    const float* wk = (const float*)d_in[2];
    const float* wv = (const float*)d_in[3];
    const float* wo = (const float*)d_in[4];

    const int B = 2, S = 2048, D = 2048, H = 32, KVH = 8;
    const int M = B * S;         // 4096
    const int NQKV = 3072;

    char* ws = (char*)d_ws;
    size_t off = 0;
    auto alloc = [&](size_t bytes) {
        void* p = ws + off;
        off += (bytes + 255) & ~(size_t)255;
        return p;
    };
    u16* xb    = (u16*)alloc((size_t)M * D * 2);        // 16 MB; reused as AO
    u16* wqkvb = (u16*)alloc((size_t)NQKV * D * 2);     // 12 MB; reused as VT
    u16* wob   = (u16*)alloc((size_t)D * D * 2);        // 8 MB
    u16* QKV   = (u16*)alloc((size_t)M * NQKV * 2);     // 24 MB
    u16* AO = xb;      // xb dead after QKV GEMM
    u16* VT = wqkvb;   // wqkvb dead after QKV GEMM

    cast_all<<<dim3(9216), 256, 0, stream>>>(x, wq, wk, wv, wo, xb, wqkvb, wob);

    gemm_bt128<<<dim3(NQKV / 128, M / 128), 256, 0, stream>>>(xb, wqkvb, QKV, M, NQKV, D, 0);

    const float sscale = 0.125f * LOG2E;
    rope_vtrans<<<dim3(5632), 256, 0, stream>>>(QKV, VT, sscale);

    attn_kernel<<<dim3(S / 128, H, B), 256, 0, stream>>>(QKV, VT, AO);

    gemm_bt128<<<dim3(D / 128, M / 128), 256, 0, stream>>>(AO, wob, d_out, M, D, D, 1);
}

// Round 2
// 375.912 us; speedup vs baseline: 1.0037x; 1.0037x over previous
//
#include <hip/hip_runtime.h>

typedef unsigned short u16;
typedef __attribute__((ext_vector_type(8))) short bf16x8;
typedef __attribute__((ext_vector_type(4))) float f32x4;

#define LOG2E 1.44269504088896340736f

__device__ inline u16 f2b(float f) {
    unsigned int u = __builtin_bit_cast(unsigned int, f);
    unsigned int r = u + 0x7fffu + ((u >> 16) & 1u);
    return (u16)(r >> 16);
}
__device__ inline float b2f(u16 h) {
    unsigned int u = ((unsigned int)h) << 16;
    return __builtin_bit_cast(float, u);
}

#define GLOAD_LDS16(g, l) \
    __builtin_amdgcn_global_load_lds( \
        (const __attribute__((address_space(1))) unsigned int*)(g), \
        (__attribute__((address_space(3))) unsigned int*)(l), 16, 0, 0)

// ---------------- fused cast fp32 -> bf16 for all 5 inputs, 8 elems/thread ----
// element boundaries: x 8388608 | wq 4194304 | wk 1048576 | wv 1048576 | wo 4194304
// wqkvb [3072 x 2048]: Q rows off 0, K rows off 4194304, V rows off 5242880.
__global__ __launch_bounds__(256) void cast_all(
    const float* __restrict__ x, const float* __restrict__ wq,
    const float* __restrict__ wk, const float* __restrict__ wv,
    const float* __restrict__ wo, u16* __restrict__ xb,
    u16* __restrict__ wqkvb, u16* __restrict__ wob) {
    long i = ((long)blockIdx.x * 256 + threadIdx.x) * 8;
    const float* s;
    u16* d;
    if (i < 8388608)       { s = x  + i;              d = xb + i; }
    else if (i < 12582912) { s = wq + (i - 8388608);  d = wqkvb + (i - 8388608); }
    else if (i < 13631488) { s = wk + (i - 12582912); d = wqkvb + 4194304 + (i - 12582912); }
    else if (i < 14680064) { s = wv + (i - 13631488); d = wqkvb + 5242880 + (i - 13631488); }
    else                   { s = wo + (i - 14680064); d = wob + (i - 14680064); }
    float4 v0 = *(const float4*)s;
    float4 v1 = *(const float4*)(s + 4);
    ushort4 o0 = make_ushort4(f2b(v0.x), f2b(v0.y), f2b(v0.z), f2b(v0.w));
    ushort4 o1 = make_ushort4(f2b(v1.x), f2b(v1.y), f2b(v1.z), f2b(v1.w));
    *(ushort4*)d = o0;
    *(ushort4*)(d + 4) = o1;
}

// ---------------- fused RoPE (Q+K) and V-transpose in one launch ----------------
// blocks [0,5120): rope, 8 elems/thread. blocks [5120,5632): vtrans 64x64 tile.
__global__ __launch_bounds__(256) void rope_vtrans(
    u16* __restrict__ qkv, u16* __restrict__ VT, float qscale) {
    const int S = 2048, RS = 3072;
    int tid = threadIdx.x;
    if (blockIdx.x < 5120) {
        int idx = blockIdx.x * 256 + tid;   // < 4096*320
        int row = idx / 320;
        int rem = idx - row * 320;
        int head = rem >> 3, chunk = rem & 7;
        int pos = row & 2047;
        int coloff;
        float scale;
        if (head < 32) { coloff = head * 64;               scale = qscale; }
        else           { coloff = 2048 + (head - 32) * 64; scale = 1.0f; }
        u16* p = qkv + (size_t)row * RS + coloff + chunk * 8;
        bf16x8 v = *(bf16x8*)p;
        float t0 = exp2f((float)(chunk * 4) * -0.41524101186092f);
        const float tc[4] = {1.0f, 0.74989420933246f, 0.56234132519035f, 0.42169650342858f};
        float fpos = (float)pos;
        #pragma unroll
        for (int i = 0; i < 4; i++) {
            float f = fpos * (t0 * tc[i]);
            float rev = f * 0.15915494309189535f;  // radians -> revolutions
            rev = rev - floorf(rev);
            float sn = __builtin_amdgcn_sinf(rev);
            float cs = __builtin_amdgcn_cosf(rev);
            float e0 = b2f((u16)v[2 * i]), e1 = b2f((u16)v[2 * i + 1]);
            v[2 * i]     = (short)f2b((e0 * cs - e1 * sn) * scale);
            v[2 * i + 1] = (short)f2b((e1 * cs + e0 * sn) * scale);
        }
        *(bf16x8*)p = v;
    } else {
        int bid = blockIdx.x - 5120;        // 0..511
        int st = bid & 31, g = (bid >> 5) & 7, b = bid >> 8;
        __shared__ u16 T[64 * 72];
        for (int c = tid; c < 512; c += 256) {
            int sr = c >> 3, dc = (c & 7) * 8;
            *(bf16x8*)&T[sr * 72 + dc] =
                *(const bf16x8*)(qkv + ((size_t)b * S + st * 64 + sr) * RS + 2560 + g * 64 + dc);
        }
        __syncthreads();
        for (int c = tid; c < 512; c += 256) {
            int d = c >> 3, sc = (c & 7) * 8;
            bf16x8 o;
            #pragma unroll
            for (int j = 0; j < 8; j++) o[j] = (short)T[(sc + j) * 72 + d];
            *(bf16x8*)(VT + ((size_t)((b * 8 + g) * 64 + d)) * S + st * 64 + sc) = o;
        }
    }
}

// ---------------- GEMM m97-style: C[M,N] = A[M,K]*B[N,K]^T ----------------
// ROUND-1: XCD-aware bijective block swizzle (T1). Grids are 768/512 blocks,
// both %8==0, so chunked remap (bid%8)*cpx + bid/8 is bijective: each XCD's
// private L2 sees a contiguous chunk of output tiles -> neighbor tiles share
// A-row / B-col panels in L2.
__global__ __launch_bounds__(256) void gemm_bt128(
    const u16* __restrict__ A, const u16* __restrict__ B, void* __restrict__ Cv,
    int M, int N, int K, int c_is_f32) {
    __shared__ u16 As[128 * 32];
    __shared__ u16 Bs[128 * 32];
    const int tid = threadIdx.x;
    const int lane = tid & 63, wave = tid >> 6;
    const int ln = lane & 15, quad = lane >> 4;
    const int wm = wave >> 1, wn = wave & 1;

    const int gx = gridDim.x;
    const int nwg = gx * gridDim.y;
    const int bid = blockIdx.y * gx + blockIdx.x;
    const int cpx = nwg >> 3;
    const int swz = (bid & 7) * cpx + (bid >> 3);
    const int m0 = (swz / gx) * 128, n0 = (swz % gx) * 128;

    const int srow = wave * 16 + (lane >> 2);
    const int skc = (lane & 3) * 8;
    const u16* Ag = A + (size_t)(m0 + srow) * K + skc;
    const u16* Bg = B + (size_t)(n0 + srow) * K + skc;

    f32x4 acc[4][4] = {};
    for (int k0 = 0; k0 < K; k0 += 32) {
        #pragma unroll
        for (int t = 0; t < 2; t++) {
            GLOAD_LDS16(Ag + (size_t)t * 64 * K + k0, As + t * 2048 + wave * 512);
            GLOAD_LDS16(Bg + (size_t)t * 64 * K + k0, Bs + t * 2048 + wave * 512);
        }
        __syncthreads();

        bf16x8 af[4], bfr[4];
        #pragma unroll
        for (int i = 0; i < 4; i++) {
            af[i]  = *(const bf16x8*)&As[(wm * 64 + i * 16 + ln) * 32 + quad * 8];
            bfr[i] = *(const bf16x8*)&Bs[(wn * 64 + i * 16 + ln) * 32 + quad * 8];
        }
        #pragma unroll
        for (int mi = 0; mi < 4; mi++)
            #pragma unroll
            for (int nt = 0; nt < 4; nt++)
                acc[mi][nt] = __builtin_amdgcn_mfma_f32_16x16x32_bf16(
                    af[mi], bfr[nt], acc[mi][nt], 0, 0, 0);
        __syncthreads();
    }

    #pragma unroll
    for (int mi = 0; mi < 4; mi++)
        #pragma unroll
        for (int nt = 0; nt < 4; nt++)
            #pragma unroll
            for (int r = 0; r < 4; r++) {
                int row = m0 + wm * 64 + mi * 16 + quad * 4 + r;
                int col = n0 + wn * 64 + nt * 16 + ln;
                float v = acc[mi][nt][r];
                if (c_is_f32) ((float*)Cv)[(size_t)row * N + col] = v;
                else          ((u16*)Cv)[(size_t)row * N + col] = f2b(v);
            }
}

// ---------------- Flash attention, GQA, causal, fused paired q-tiles ---------
// grid: (S/128, H, B). Q pre-scaled by (1/8)*log2e in RoPE. No online max.
// ROUND-1 CHANGES (latency-bound profile: MfmaUtil 11.6 / VALU 28 / HBM 5%):
//  - Ks double-buffered: ONE barrier per body (was two); the K stage-write
//    targets the buffer nobody reads this body -> off the critical path.
//  - V fragments prefetched one full tile ahead (loads issued right after the
//    PV phase consumes the previous set) -> full body of compute hides L2/HBM
//    latency. vr is loop-carried, no extra register cost vs body-local.
//  - K prefetch moves to 2-ahead to feed the double buffer.
__global__ __launch_bounds__(256) void attn_kernel(
    const u16* __restrict__ QKV, const u16* __restrict__ VT, u16* __restrict__ O) {
    const int S = 2048, RS = 3072, DO = 2048;
    const int b = blockIdx.z, h = blockIdx.y, p = blockIdx.x;
    const int g = h >> 2;
    const int qtl = p, qth = (S / 64 - 1) - p;   // qtl <= 15 < 16 <= qth
    const int tid = threadIdx.x;
    const int lane = tid & 63, wave = tid >> 6;
    const int ln = lane & 15, quad = lane >> 4;

    __shared__ u16 Ks[2][64 * 72];
    __shared__ u16 Psh[64 * 68];
    __shared__ u16 Psl[64 * 68];

    const u16* Qb = QKV + (size_t)b * S * RS + h * 64 + quad * 8;
    bf16x8 aqh0 = *(const bf16x8*)(Qb + (size_t)(qth * 64 + wave * 16 + ln) * RS);
    bf16x8 aqh1 = *(const bf16x8*)(Qb + (size_t)(qth * 64 + wave * 16 + ln) * RS + 32);
    bf16x8 aql0 = *(const bf16x8*)(Qb + (size_t)(qtl * 64 + wave * 16 + ln) * RS);
    bf16x8 aql1 = *(const bf16x8*)(Qb + (size_t)(qtl * 64 + wave * 16 + ln) * RS + 32);

    const u16* Kb = QKV + (size_t)b * S * RS + 2048 + g * 64;
    const u16* VTb = VT + (size_t)(b * 8 + g) * 64 * S;

    const bf16x8 vones = {0x3F80, 0x3F80, 0x3F80, 0x3F80, 0x3F80, 0x3F80, 0x3F80, 0x3F80};

    f32x4 acch[5] = {}, accl[5] = {};  // [0..3]=O tiles, [4]=row-sum l

    const int r0 = tid >> 3;            // 0..31
    const int dc0 = (tid & 7) * 8;
    bf16x8 kreg0, kreg1;
    bf16x8 vr[2][4];                    // V fragments for the CURRENT tile
    auto loadK = [&](int kt) {
        kreg0 = *(const bf16x8*)(Kb + (size_t)(kt * 64 + r0) * RS + dc0);
        kreg1 = *(const bf16x8*)(Kb + (size_t)(kt * 64 + r0 + 32) * RS + dc0);
    };
    auto loadV = [&](int kt) {
        #pragma unroll
        for (int kk = 0; kk < 2; kk++)
            #pragma unroll
            for (int nt = 0; nt < 4; nt++)
                vr[kk][nt] = *(const bf16x8*)(VTb + (size_t)(nt * 16 + ln) * S
                                              + kt * 64 + kk * 32 + quad * 8);
    };

    // body invariants at entry: Ks[kt&1] holds K-tile kt (staged last body or
    // prologue); kreg holds K-tile kt+1 (if any); vr holds V-tile kt.
    auto body = [&](int kt, bool DUAL, bool MH, bool ML) {
        u16* KsC = &Ks[kt & 1][0];
        u16* KsN = &Ks[(kt & 1) ^ 1][0];
        if (kt < qth) {   // stage NEXT K-tile; readers of KsN finished last body
            *(bf16x8*)&KsN[r0 * 72 + dc0] = kreg0;
            *(bf16x8*)&KsN[(r0 + 32) * 72 + dc0] = kreg1;
        }
        if (kt + 2 <= qth) loadK(kt + 2);

        f32x4 sh[4] = {}, sl[4] = {};
        __builtin_amdgcn_s_setprio(1);
        #pragma unroll
        for (int nt = 0; nt < 4; nt++) {
            bf16x8 bk0 = *(const bf16x8*)&KsC[(nt * 16 + ln) * 72 + quad * 8];
            bf16x8 bk1 = *(const bf16x8*)&KsC[(nt * 16 + ln) * 72 + 32 + quad * 8];
            sh[nt] = __builtin_amdgcn_mfma_f32_16x16x32_bf16(aqh0, bk0, sh[nt], 0, 0, 0);
            sh[nt] = __builtin_amdgcn_mfma_f32_16x16x32_bf16(aqh1, bk1, sh[nt], 0, 0, 0);
            if (DUAL) {
                sl[nt] = __builtin_amdgcn_mfma_f32_16x16x32_bf16(aql0, bk0, sl[nt], 0, 0, 0);
                sl[nt] = __builtin_amdgcn_mfma_f32_16x16x32_bf16(aql1, bk1, sl[nt], 0, 0, 0);
            }
        }
        __builtin_amdgcn_s_setprio(0);

        if (MH) {
            #pragma unroll
            for (int nt = 0; nt < 4; nt++)
                #pragma unroll
                for (int r = 0; r < 4; r++)
                    if (nt * 16 + ln > wave * 16 + quad * 4 + r) sh[nt][r] = -INFINITY;
        }
        #pragma unroll
        for (int nt = 0; nt < 4; nt++)
            #pragma unroll
            for (int r = 0; r < 4; r++) {
                float pv = exp2f(sh[nt][r]);
                Psh[(wave * 16 + quad * 4 + r) * 68 + nt * 16 + ln] =
                    (u16)(__builtin_bit_cast(unsigned int, pv) >> 16);
            }
        if (DUAL) {
            if (ML) {
                #pragma unroll
                for (int nt = 0; nt < 4; nt++)
                    #pragma unroll
                    for (int r = 0; r < 4; r++)
                        if (nt * 16 + ln > wave * 16 + quad * 4 + r) sl[nt][r] = -INFINITY;
            }
            #pragma unroll
            for (int nt = 0; nt < 4; nt++)
                #pragma unroll
                for (int r = 0; r < 4; r++) {
                    float pv = exp2f(sl[nt][r]);
                    Psl[(wave * 16 + quad * 4 + r) * 68 + nt * 16 + ln] =
                        (u16)(__builtin_bit_cast(unsigned int, pv) >> 16);
                }
        }
        // no barrier: Ps rows are wave-private (same-wave LDS ordering)

        __builtin_amdgcn_s_setprio(1);
        #pragma unroll
        for (int kk = 0; kk < 2; kk++) {
            bf16x8 aph = *(const bf16x8*)&Psh[(wave * 16 + ln) * 68 + kk * 32 + quad * 8];
            #pragma unroll
            for (int nt = 0; nt < 4; nt++)
                acch[nt] = __builtin_amdgcn_mfma_f32_16x16x32_bf16(aph, vr[kk][nt], acch[nt], 0, 0, 0);
            acch[4] = __builtin_amdgcn_mfma_f32_16x16x32_bf16(aph, vones, acch[4], 0, 0, 0);
            if (DUAL) {
                bf16x8 apl = *(const bf16x8*)&Psl[(wave * 16 + ln) * 68 + kk * 32 + quad * 8];
                #pragma unroll
                for (int nt = 0; nt < 4; nt++)
                    accl[nt] = __builtin_amdgcn_mfma_f32_16x16x32_bf16(apl, vr[kk][nt], accl[nt], 0, 0, 0);
                accl[4] = __builtin_amdgcn_mfma_f32_16x16x32_bf16(apl, vones, accl[4], 0, 0, 0);
            }
        }
        __builtin_amdgcn_s_setprio(0);

        if (kt < qth) loadV(kt + 1);   // prefetch next V; whole next body hides it
        __syncthreads();               // single barrier per body
    };

    // prologue: stage tile 0 into Ks[0], prefetch K-tile 1 and V-tile 0.
    loadK(0);
    loadV(0);
    *(bf16x8*)&Ks[0][r0 * 72 + dc0] = kreg0;
    *(bf16x8*)&Ks[0][(r0 + 32) * 72 + dc0] = kreg1;
    loadK(1);
    __syncthreads();

    for (int kt = 0; kt < qtl; kt++) body(kt, true, false, false);   // dual, unmasked
    body(qtl, true, false, true);                                    // dual, qtl diagonal
    for (int kt = qtl + 1; kt < qth; kt++) body(kt, false, false, false); // single
    body(qth, false, true, false);                                   // single, qth diagonal

    // epilogue
    u16* Ob = O + (size_t)b * S * DO + h * 64;
    #pragma unroll
    for (int r = 0; r < 4; r++) {
        float invh = 1.0f / acch[4][r];
        float invl = 1.0f / accl[4][r];
        int qh = qth * 64 + wave * 16 + quad * 4 + r;
        int ql = qtl * 64 + wave * 16 + quad * 4 + r;
        #pragma unroll
        for (int nt = 0; nt < 4; nt++) {
            Ob[(size_t)qh * DO + nt * 16 + ln] = f2b(acch[nt][r] * invh);
            Ob[(size_t)ql * DO + nt * 16 + ln] = f2b(accl[nt][r] * invl);
        }
    }
}

extern "C" void kernel_launch(void* const* d_in, const int* in_sizes, int n_in,
                              void* d_out, int out_size, void* d_ws, size_t ws_size,
                              hipStream_t stream) {
    const float* x  = (const float*)d_in[0];
    const float* wq = (const float*)d_in[1];
    const float* wk = (const float*)d_in[2];
    const float* wv = (const float*)d_in[3];
    const float* wo = (const float*)d_in[4];

    const int B = 2, S = 2048, D = 2048, H = 32, KVH = 8;
    const int M = B * S;         // 4096
    const int NQKV = 3072;

    char* ws = (char*)d_ws;
    size_t off = 0;
    auto alloc = [&](size_t bytes) {
        void* p = ws + off;
        off += (bytes + 255) & ~(size_t)255;
        return p;
    };
    u16* xb    = (u16*)alloc((size_t)M * D * 2);        // 16 MB; reused as AO
    u16* wqkvb = (u16*)alloc((size_t)NQKV * D * 2);     // 12 MB; reused as VT
    u16* wob   = (u16*)alloc((size_t)D * D * 2);        // 8 MB
    u16* QKV   = (u16*)alloc((size_t)M * NQKV * 2);     // 24 MB
    u16* AO = xb;      // xb dead after QKV GEMM
    u16* VT = wqkvb;   // wqkvb dead after QKV GEMM

    cast_all<<<dim3(9216), 256, 0, stream>>>(x, wq, wk, wv, wo, xb, wqkvb, wob);

    gemm_bt128<<<dim3(NQKV / 128, M / 128), 256, 0, stream>>>(xb, wqkvb, QKV, M, NQKV, D, 0);

    const float sscale = 0.125f * LOG2E;
    rope_vtrans<<<dim3(5632), 256, 0, stream>>>(QKV, VT, sscale);

    attn_kernel<<<dim3(S / 128, H, B), 256, 0, stream>>>(QKV, VT, AO);

    gemm_bt128<<<dim3(D / 128, M / 128), 256, 0, stream>>>(AO, wob, d_out, M, D, D, 1);
}

// Round 3
// 372.913 us; speedup vs baseline: 1.0118x; 1.0080x over previous
//
#include <hip/hip_runtime.h>

typedef unsigned short u16;
typedef __attribute__((ext_vector_type(8))) short bf16x8;
typedef __attribute__((ext_vector_type(4))) float f32x4;

#define LOG2E 1.44269504088896340736f

__device__ inline u16 f2b(float f) {
    unsigned int u = __builtin_bit_cast(unsigned int, f);
    unsigned int r = u + 0x7fffu + ((u >> 16) & 1u);
    return (u16)(r >> 16);
}
__device__ inline float b2f(u16 h) {
    unsigned int u = ((unsigned int)h) << 16;
    return __builtin_bit_cast(float, u);
}

#define GLOAD_LDS16(g, l) \
    __builtin_amdgcn_global_load_lds( \
        (const __attribute__((address_space(1))) unsigned int*)(g), \
        (__attribute__((address_space(3))) unsigned int*)(l), 16, 0, 0)

// ---------------- fused cast fp32 -> bf16 for all 5 inputs, 8 elems/thread ----
// element boundaries: x 8388608 | wq 4194304 | wk 1048576 | wv 1048576 | wo 4194304
// wqkvb [3072 x 2048]: Q rows off 0, K rows off 4194304, V rows off 5242880.
__global__ __launch_bounds__(256) void cast_all(
    const float* __restrict__ x, const float* __restrict__ wq,
    const float* __restrict__ wk, const float* __restrict__ wv,
    const float* __restrict__ wo, u16* __restrict__ xb,
    u16* __restrict__ wqkvb, u16* __restrict__ wob) {
    long i = ((long)blockIdx.x * 256 + threadIdx.x) * 8;
    const float* s;
    u16* d;
    if (i < 8388608)       { s = x  + i;              d = xb + i; }
    else if (i < 12582912) { s = wq + (i - 8388608);  d = wqkvb + (i - 8388608); }
    else if (i < 13631488) { s = wk + (i - 12582912); d = wqkvb + 4194304 + (i - 12582912); }
    else if (i < 14680064) { s = wv + (i - 13631488); d = wqkvb + 5242880 + (i - 13631488); }
    else                   { s = wo + (i - 14680064); d = wob + (i - 14680064); }
    float4 v0 = *(const float4*)s;
    float4 v1 = *(const float4*)(s + 4);
    ushort4 o0 = make_ushort4(f2b(v0.x), f2b(v0.y), f2b(v0.z), f2b(v0.w));
    ushort4 o1 = make_ushort4(f2b(v1.x), f2b(v1.y), f2b(v1.z), f2b(v1.w));
    *(ushort4*)d = o0;
    *(ushort4*)(d + 4) = o1;
}

// ---------------- fused RoPE (Q+K) and V-transpose in one launch ----------------
// blocks [0,5120): rope, 8 elems/thread. blocks [5120,5632): vtrans 64x64 tile.
__global__ __launch_bounds__(256) void rope_vtrans(
    u16* __restrict__ qkv, u16* __restrict__ VT, float qscale) {
    const int S = 2048, RS = 3072;
    int tid = threadIdx.x;
    if (blockIdx.x < 5120) {
        int idx = blockIdx.x * 256 + tid;   // < 4096*320
        int row = idx / 320;
        int rem = idx - row * 320;
        int head = rem >> 3, chunk = rem & 7;
        int pos = row & 2047;
        int coloff;
        float scale;
        if (head < 32) { coloff = head * 64;               scale = qscale; }
        else           { coloff = 2048 + (head - 32) * 64; scale = 1.0f; }
        u16* p = qkv + (size_t)row * RS + coloff + chunk * 8;
        bf16x8 v = *(bf16x8*)p;
        float t0 = exp2f((float)(chunk * 4) * -0.41524101186092f);
        const float tc[4] = {1.0f, 0.74989420933246f, 0.56234132519035f, 0.42169650342858f};
        float fpos = (float)pos;
        #pragma unroll
        for (int i = 0; i < 4; i++) {
            float f = fpos * (t0 * tc[i]);
            float rev = f * 0.15915494309189535f;  // radians -> revolutions
            rev = rev - floorf(rev);
            float sn = __builtin_amdgcn_sinf(rev);
            float cs = __builtin_amdgcn_cosf(rev);
            float e0 = b2f((u16)v[2 * i]), e1 = b2f((u16)v[2 * i + 1]);
            v[2 * i]     = (short)f2b((e0 * cs - e1 * sn) * scale);
            v[2 * i + 1] = (short)f2b((e1 * cs + e0 * sn) * scale);
        }
        *(bf16x8*)p = v;
    } else {
        int bid = blockIdx.x - 5120;        // 0..511
        int st = bid & 31, g = (bid >> 5) & 7, b = bid >> 8;
        __shared__ u16 T[64 * 72];
        for (int c = tid; c < 512; c += 256) {
            int sr = c >> 3, dc = (c & 7) * 8;
            *(bf16x8*)&T[sr * 72 + dc] =
                *(const bf16x8*)(qkv + ((size_t)b * S + st * 64 + sr) * RS + 2560 + g * 64 + dc);
        }
        __syncthreads();
        for (int c = tid; c < 512; c += 256) {
            int d = c >> 3, sc = (c & 7) * 8;
            bf16x8 o;
            #pragma unroll
            for (int j = 0; j < 8; j++) o[j] = (short)T[(sc + j) * 72 + d];
            *(bf16x8*)(VT + ((size_t)((b * 8 + g) * 64 + d)) * S + st * 64 + sc) = o;
        }
    }
}

// ---------------- GEMM m97-style: C[M,N] = A[M,K]*B[N,K]^T ----------------
// XCD-aware bijective block swizzle (T1); grids 768/512 blocks, both %8==0.
__global__ __launch_bounds__(256) void gemm_bt128(
    const u16* __restrict__ A, const u16* __restrict__ B, void* __restrict__ Cv,
    int M, int N, int K, int c_is_f32) {
    __shared__ u16 As[128 * 32];
    __shared__ u16 Bs[128 * 32];
    const int tid = threadIdx.x;
    const int lane = tid & 63, wave = tid >> 6;
    const int ln = lane & 15, quad = lane >> 4;
    const int wm = wave >> 1, wn = wave & 1;

    const int gx = gridDim.x;
    const int nwg = gx * gridDim.y;
    const int bid = blockIdx.y * gx + blockIdx.x;
    const int cpx = nwg >> 3;
    const int swz = (bid & 7) * cpx + (bid >> 3);
    const int m0 = (swz / gx) * 128, n0 = (swz % gx) * 128;

    const int srow = wave * 16 + (lane >> 2);
    const int skc = (lane & 3) * 8;
    const u16* Ag = A + (size_t)(m0 + srow) * K + skc;
    const u16* Bg = B + (size_t)(n0 + srow) * K + skc;

    f32x4 acc[4][4] = {};
    for (int k0 = 0; k0 < K; k0 += 32) {
        #pragma unroll
        for (int t = 0; t < 2; t++) {
            GLOAD_LDS16(Ag + (size_t)t * 64 * K + k0, As + t * 2048 + wave * 512);
            GLOAD_LDS16(Bg + (size_t)t * 64 * K + k0, Bs + t * 2048 + wave * 512);
        }
        __syncthreads();

        bf16x8 af[4], bfr[4];
        #pragma unroll
        for (int i = 0; i < 4; i++) {
            af[i]  = *(const bf16x8*)&As[(wm * 64 + i * 16 + ln) * 32 + quad * 8];
            bfr[i] = *(const bf16x8*)&Bs[(wn * 64 + i * 16 + ln) * 32 + quad * 8];
        }
        #pragma unroll
        for (int mi = 0; mi < 4; mi++)
            #pragma unroll
            for (int nt = 0; nt < 4; nt++)
                acc[mi][nt] = __builtin_amdgcn_mfma_f32_16x16x32_bf16(
                    af[mi], bfr[nt], acc[mi][nt], 0, 0, 0);
        __syncthreads();
    }

    #pragma unroll
    for (int mi = 0; mi < 4; mi++)
        #pragma unroll
        for (int nt = 0; nt < 4; nt++)
            #pragma unroll
            for (int r = 0; r < 4; r++) {
                int row = m0 + wm * 64 + mi * 16 + quad * 4 + r;
                int col = n0 + wn * 64 + nt * 16 + ln;
                float v = acc[mi][nt][r];
                if (c_is_f32) ((float*)Cv)[(size_t)row * N + col] = v;
                else          ((u16*)Cv)[(size_t)row * N + col] = f2b(v);
            }
}

// ---------------- Flash attention, GQA, causal, fused paired q-tiles ---------
// ROUND-2 RESTRUCTURE (latency-bound evidence: occupancy ~5.7 waves/CU, no
// throughput pipe >29%, round-1 barrier/prefetch changes were neutral):
//  - 512-thread blocks, 8 waves: waves 0-3 = head 2*hp, waves 4-7 = head
//    2*hp+1 (same KV group g = hp>>1). 2 waves/SIMD per resident block (was 1)
//    -> latency hiding; K staged ONCE per block for both heads (half LDS+HBM
//    K traffic). Grid 1024 -> 512 with XCD-chunked swizzle: each XCD owns
//    contiguous swz range = 2 (b,g) K/V slabs -> L2-local.
//  - Ks: stride 64 u16 (no pad) + XOR swizzle slot^=(row&7) on BOTH write and
//    read (G4: [64][128B] rows were an ~8-way conflict at stride-72; swizzle
//    makes reads 2-way = free). Double-buffered, one barrier per body.
//  - V fragments direct from global (L2-resident), prefetched one tile ahead.
__global__ __launch_bounds__(512) void attn_kernel(
    const u16* __restrict__ QKV, const u16* __restrict__ VT, u16* __restrict__ O) {
    const int S = 2048, RS = 3072, DO = 2048;
    const int bid = blockIdx.x;                 // 0..511
    const int swz = (bid & 7) * 64 + (bid >> 3);
    const int p = swz & 15, hp = (swz >> 4) & 15, b = swz >> 8;
    const int g = hp >> 1;
    const int qtl = p, qth = 31 - p;            // qtl <= 15 < 16 <= qth
    const int tid = threadIdx.x;
    const int lane = tid & 63, wave = tid >> 6; // wave 0..7
    const int hw = wave >> 2, lw = wave & 3;    // head-half, local wave
    const int h = hp * 2 + hw;
    const int ln = lane & 15, quad = lane >> 4;

    __shared__ u16 Ks[2][64 * 64];              // swizzled, stride 64
    __shared__ u16 Ps[4][64 * 68];              // [hw*2]=high-tile P, [hw*2+1]=low
    u16* Psh = &Ps[hw * 2 + 0][0];
    u16* Psl = &Ps[hw * 2 + 1][0];

    const u16* Qb = QKV + (size_t)b * S * RS + h * 64 + quad * 8;
    bf16x8 aqh0 = *(const bf16x8*)(Qb + (size_t)(qth * 64 + lw * 16 + ln) * RS);
    bf16x8 aqh1 = *(const bf16x8*)(Qb + (size_t)(qth * 64 + lw * 16 + ln) * RS + 32);
    bf16x8 aql0 = *(const bf16x8*)(Qb + (size_t)(qtl * 64 + lw * 16 + ln) * RS);
    bf16x8 aql1 = *(const bf16x8*)(Qb + (size_t)(qtl * 64 + lw * 16 + ln) * RS + 32);

    const u16* Kb = QKV + (size_t)b * S * RS + 2048 + g * 64;
    const u16* VTb = VT + (size_t)(b * 8 + g) * 64 * S;

    const bf16x8 vones = {0x3F80, 0x3F80, 0x3F80, 0x3F80, 0x3F80, 0x3F80, 0x3F80, 0x3F80};

    f32x4 acch[5] = {}, accl[5] = {};  // [0..3]=O tiles, [4]=row-sum l

    // K staging: each of 512 threads owns one 16B chunk of the 64x64 K tile.
    const int kr = tid >> 3;            // 0..63 (row)
    const int ks = tid & 7;             // 16B slot in row
    const int kswz = ((ks ^ (kr & 7)) * 8); // swizzled u16 offset in row
    bf16x8 kreg;
    bf16x8 vr[2][4];                    // V fragments for the CURRENT tile
    auto loadK = [&](int kt) {
        kreg = *(const bf16x8*)(Kb + (size_t)(kt * 64 + kr) * RS + ks * 8);
    };
    auto loadV = [&](int kt) {
        #pragma unroll
        for (int kk = 0; kk < 2; kk++)
            #pragma unroll
            for (int nt = 0; nt < 4; nt++)
                vr[kk][nt] = *(const bf16x8*)(VTb + (size_t)(nt * 16 + ln) * S
                                              + kt * 64 + kk * 32 + quad * 8);
    };

    // body invariants at entry: Ks[kt&1] holds K-tile kt; kreg holds K-tile
    // kt+1 (if any); vr holds V-tile kt.
    auto body = [&](int kt, bool DUAL, bool MH, bool ML) {
        u16* KsC = &Ks[kt & 1][0];
        u16* KsN = &Ks[(kt & 1) ^ 1][0];
        if (kt < qth) {   // stage NEXT K-tile; readers of KsN finished last body
            *(bf16x8*)&KsN[kr * 64 + kswz] = kreg;
        }
        if (kt + 2 <= qth) loadK(kt + 2);

        const int rsw = ln & 7;         // read-side row XOR (row = nt*16+ln)
        f32x4 sh[4] = {}, sl[4] = {};
        __builtin_amdgcn_s_setprio(1);
        #pragma unroll
        for (int nt = 0; nt < 4; nt++) {
            bf16x8 bk0 = *(const bf16x8*)&KsC[(nt * 16 + ln) * 64 + ((quad ^ rsw) * 8)];
            bf16x8 bk1 = *(const bf16x8*)&KsC[(nt * 16 + ln) * 64 + (((quad + 4) ^ rsw) * 8)];
            sh[nt] = __builtin_amdgcn_mfma_f32_16x16x32_bf16(aqh0, bk0, sh[nt], 0, 0, 0);
            sh[nt] = __builtin_amdgcn_mfma_f32_16x16x32_bf16(aqh1, bk1, sh[nt], 0, 0, 0);
            if (DUAL) {
                sl[nt] = __builtin_amdgcn_mfma_f32_16x16x32_bf16(aql0, bk0, sl[nt], 0, 0, 0);
                sl[nt] = __builtin_amdgcn_mfma_f32_16x16x32_bf16(aql1, bk1, sl[nt], 0, 0, 0);
            }
        }
        __builtin_amdgcn_s_setprio(0);

        if (MH) {
            #pragma unroll
            for (int nt = 0; nt < 4; nt++)
                #pragma unroll
                for (int r = 0; r < 4; r++)
                    if (nt * 16 + ln > lw * 16 + quad * 4 + r) sh[nt][r] = -INFINITY;
        }
        #pragma unroll
        for (int nt = 0; nt < 4; nt++)
            #pragma unroll
            for (int r = 0; r < 4; r++) {
                float pv = exp2f(sh[nt][r]);
                Psh[(lw * 16 + quad * 4 + r) * 68 + nt * 16 + ln] =
                    (u16)(__builtin_bit_cast(unsigned int, pv) >> 16);
            }
        if (DUAL) {
            if (ML) {
                #pragma unroll
                for (int nt = 0; nt < 4; nt++)
                    #pragma unroll
                    for (int r = 0; r < 4; r++)
                        if (nt * 16 + ln > lw * 16 + quad * 4 + r) sl[nt][r] = -INFINITY;
            }
            #pragma unroll
            for (int nt = 0; nt < 4; nt++)
                #pragma unroll
                for (int r = 0; r < 4; r++) {
                    float pv = exp2f(sl[nt][r]);
                    Psl[(lw * 16 + quad * 4 + r) * 68 + nt * 16 + ln] =
                        (u16)(__builtin_bit_cast(unsigned int, pv) >> 16);
                }
        }
        // no barrier: Ps rows are wave-private (same-wave LDS ordering)

        __builtin_amdgcn_s_setprio(1);
        #pragma unroll
        for (int kk = 0; kk < 2; kk++) {
            bf16x8 aph = *(const bf16x8*)&Psh[(lw * 16 + ln) * 68 + kk * 32 + quad * 8];
            #pragma unroll
            for (int nt = 0; nt < 4; nt++)
                acch[nt] = __builtin_amdgcn_mfma_f32_16x16x32_bf16(aph, vr[kk][nt], acch[nt], 0, 0, 0);
            acch[4] = __builtin_amdgcn_mfma_f32_16x16x32_bf16(aph, vones, acch[4], 0, 0, 0);
            if (DUAL) {
                bf16x8 apl = *(const bf16x8*)&Psl[(lw * 16 + ln) * 68 + kk * 32 + quad * 8];
                #pragma unroll
                for (int nt = 0; nt < 4; nt++)
                    accl[nt] = __builtin_amdgcn_mfma_f32_16x16x32_bf16(apl, vr[kk][nt], accl[nt], 0, 0, 0);
                accl[4] = __builtin_amdgcn_mfma_f32_16x16x32_bf16(apl, vones, accl[4], 0, 0, 0);
            }
        }
        __builtin_amdgcn_s_setprio(0);

        if (kt < qth) loadV(kt + 1);   // prefetch next V; whole next body hides it
        __syncthreads();               // single barrier per body
    };

    // prologue: stage tile 0 into Ks[0], prefetch K-tile 1 and V-tile 0.
    loadK(0);
    loadV(0);
    *(bf16x8*)&Ks[0][kr * 64 + kswz] = kreg;
    loadK(1);
    __syncthreads();

    for (int kt = 0; kt < qtl; kt++) body(kt, true, false, false);   // dual, unmasked
    body(qtl, true, false, true);                                    // dual, qtl diagonal
    for (int kt = qtl + 1; kt < qth; kt++) body(kt, false, false, false); // single
    body(qth, false, true, false);                                   // single, qth diagonal

    // epilogue
    u16* Ob = O + (size_t)b * S * DO + h * 64;
    #pragma unroll
    for (int r = 0; r < 4; r++) {
        float invh = 1.0f / acch[4][r];
        float invl = 1.0f / accl[4][r];
        int qh = qth * 64 + lw * 16 + quad * 4 + r;
        int ql = qtl * 64 + lw * 16 + quad * 4 + r;
        #pragma unroll
        for (int nt = 0; nt < 4; nt++) {
            Ob[(size_t)qh * DO + nt * 16 + ln] = f2b(acch[nt][r] * invh);
            Ob[(size_t)ql * DO + nt * 16 + ln] = f2b(accl[nt][r] * invl);
        }
    }
}

extern "C" void kernel_launch(void* const* d_in, const int* in_sizes, int n_in,
                              void* d_out, int out_size, void* d_ws, size_t ws_size,
                              hipStream_t stream) {
    const float* x  = (const float*)d_in[0];
    const float* wq = (const float*)d_in[1];
    const float* wk = (const float*)d_in[2];
    const float* wv = (const float*)d_in[3];
    const float* wo = (const float*)d_in[4];

    const int B = 2, S = 2048, D = 2048, H = 32, KVH = 8;
    const int M = B * S;         // 4096
    const int NQKV = 3072;

    char* ws = (char*)d_ws;
    size_t off = 0;
    auto alloc = [&](size_t bytes) {
        void* p = ws + off;
        off += (bytes + 255) & ~(size_t)255;
        return p;
    };
    u16* xb    = (u16*)alloc((size_t)M * D * 2);        // 16 MB; reused as AO
    u16* wqkvb = (u16*)alloc((size_t)NQKV * D * 2);     // 12 MB; reused as VT
    u16* wob   = (u16*)alloc((size_t)D * D * 2);        // 8 MB
    u16* QKV   = (u16*)alloc((size_t)M * NQKV * 2);     // 24 MB
    u16* AO = xb;      // xb dead after QKV GEMM
    u16* VT = wqkvb;   // wqkvb dead after QKV GEMM

    cast_all<<<dim3(9216), 256, 0, stream>>>(x, wq, wk, wv, wo, xb, wqkvb, wob);

    gemm_bt128<<<dim3(NQKV / 128, M / 128), 256, 0, stream>>>(xb, wqkvb, QKV, M, NQKV, D, 0);

    const float sscale = 0.125f * LOG2E;
    rope_vtrans<<<dim3(5632), 256, 0, stream>>>(QKV, VT, sscale);

    attn_kernel<<<dim3(512), 512, 0, stream>>>(QKV, VT, AO);

    gemm_bt128<<<dim3(D / 128, M / 128), 256, 0, stream>>>(AO, wob, d_out, M, D, D, 1);
}

// Round 5
// 365.917 us; speedup vs baseline: 1.0311x; 1.0191x over previous
//
#include <hip/hip_runtime.h>

typedef unsigned short u16;
typedef __attribute__((ext_vector_type(8))) short bf16x8;
typedef __attribute__((ext_vector_type(4))) float f32x4;

#define LOG2E 1.44269504088896340736f

__device__ inline u16 f2b(float f) {
    unsigned int u = __builtin_bit_cast(unsigned int, f);
    unsigned int r = u + 0x7fffu + ((u >> 16) & 1u);
    return (u16)(r >> 16);
}
__device__ inline float b2f(u16 h) {
    unsigned int u = ((unsigned int)h) << 16;
    return __builtin_bit_cast(float, u);
}

#define GLOAD_LDS16(g, l) \
    __builtin_amdgcn_global_load_lds( \
        (const __attribute__((address_space(1))) unsigned int*)(g), \
        (__attribute__((address_space(3))) unsigned int*)(l), 16, 0, 0)

// ---------------- fused cast fp32 -> bf16 for all 5 inputs, 8 elems/thread ----
__global__ __launch_bounds__(256) void cast_all(
    const float* __restrict__ x, const float* __restrict__ wq,
    const float* __restrict__ wk, const float* __restrict__ wv,
    const float* __restrict__ wo, u16* __restrict__ xb,
    u16* __restrict__ wqkvb, u16* __restrict__ wob) {
    long i = ((long)blockIdx.x * 256 + threadIdx.x) * 8;
    const float* s;
    u16* d;
    if (i < 8388608)       { s = x  + i;              d = xb + i; }
    else if (i < 12582912) { s = wq + (i - 8388608);  d = wqkvb + (i - 8388608); }
    else if (i < 13631488) { s = wk + (i - 12582912); d = wqkvb + 4194304 + (i - 12582912); }
    else if (i < 14680064) { s = wv + (i - 13631488); d = wqkvb + 5242880 + (i - 13631488); }
    else                   { s = wo + (i - 14680064); d = wob + (i - 14680064); }
    float4 v0 = *(const float4*)s;
    float4 v1 = *(const float4*)(s + 4);
    ushort4 o0 = make_ushort4(f2b(v0.x), f2b(v0.y), f2b(v0.z), f2b(v0.w));
    ushort4 o1 = make_ushort4(f2b(v1.x), f2b(v1.y), f2b(v1.z), f2b(v1.w));
    *(ushort4*)d = o0;
    *(ushort4*)(d + 4) = o1;
}

// ---------------- fused RoPE (Q+K) and V-transpose in one launch ----------------
__global__ __launch_bounds__(256) void rope_vtrans(
    u16* __restrict__ qkv, u16* __restrict__ VT, float qscale) {
    const int S = 2048, RS = 3072;
    int tid = threadIdx.x;
    if (blockIdx.x < 5120) {
        int idx = blockIdx.x * 256 + tid;   // < 4096*320
        int row = idx / 320;
        int rem = idx - row * 320;
        int head = rem >> 3, chunk = rem & 7;
        int pos = row & 2047;
        int coloff;
        float scale;
        if (head < 32) { coloff = head * 64;               scale = qscale; }
        else           { coloff = 2048 + (head - 32) * 64; scale = 1.0f; }
        u16* p = qkv + (size_t)row * RS + coloff + chunk * 8;
        bf16x8 v = *(bf16x8*)p;
        float t0 = exp2f((float)(chunk * 4) * -0.41524101186092f);
        const float tc[4] = {1.0f, 0.74989420933246f, 0.56234132519035f, 0.42169650342858f};
        float fpos = (float)pos;
        #pragma unroll
        for (int i = 0; i < 4; i++) {
            float f = fpos * (t0 * tc[i]);
            float rev = f * 0.15915494309189535f;  // radians -> revolutions
            rev = rev - floorf(rev);
            float sn = __builtin_amdgcn_sinf(rev);
            float cs = __builtin_amdgcn_cosf(rev);
            float e0 = b2f((u16)v[2 * i]), e1 = b2f((u16)v[2 * i + 1]);
            v[2 * i]     = (short)f2b((e0 * cs - e1 * sn) * scale);
            v[2 * i + 1] = (short)f2b((e1 * cs + e0 * sn) * scale);
        }
        *(bf16x8*)p = v;
    } else {
        int bid = blockIdx.x - 5120;        // 0..511
        int st = bid & 31, g = (bid >> 5) & 7, b = bid >> 8;
        __shared__ u16 T[64 * 72];
        for (int c = tid; c < 512; c += 256) {
            int sr = c >> 3, dc = (c & 7) * 8;
            *(bf16x8*)&T[sr * 72 + dc] =
                *(const bf16x8*)(qkv + ((size_t)b * S + st * 64 + sr) * RS + 2560 + g * 64 + dc);
        }
        __syncthreads();
        for (int c = tid; c < 512; c += 256) {
            int d = c >> 3, sc = (c & 7) * 8;
            bf16x8 o;
            #pragma unroll
            for (int j = 0; j < 8; j++) o[j] = (short)T[(sc + j) * 72 + d];
            *(bf16x8*)(VT + ((size_t)((b * 8 + g) * 64 + d)) * S + st * 64 + sc) = o;
        }
    }
}

// ---------------- GEMM 256x256 8-phase (m201-style port): C[M,N]=A[M,K]*B[N,K]^T
// ROUND-4 FIX of the round-3 race: vmcnt is PER-WAVE; the cross-wave guarantee
// that staged LDS data is readable requires  vmcnt -> s_barrier -> ds_read.
// Round-3 had vmcnt -> ds_read -> barrier (wave 0 read wave 7's unstaged rows).
// Now: counted vmcnt sits at the END of P4 (before the tile-boundary barrier):
//   at P4(u) tail, outstanding (oldest..newest) = B(u+1):4, A(u+1):4, B(u+2):4;
//   vmcnt(4) -> the 8 loads P1(u+1) reads have landed; B(u+2) stays in flight.
//   u==NT-2: no B(u+2) staged -> vmcnt(0). Prologue: stage B0,A0,B1; vmcnt(4);
//   barrier. BAR() includes sched_barrier(0) so the compiler cannot hoist
//   ds_reads above the s_barrier (s_barrier is IntrNoMem to LLVM).
#define MMAQ(MH, NH, AR, BR) do { \
    __builtin_amdgcn_s_setprio(1); \
    _Pragma("unroll") \
    for (int m2 = 0; m2 < 4; m2++) { \
        _Pragma("unroll") \
        for (int n2 = 0; n2 < 2; n2++) { \
            acc[(MH)*4+m2][(NH)*2+n2] = __builtin_amdgcn_mfma_f32_16x16x32_bf16( \
                AR[m2][0], BR[n2][0], acc[(MH)*4+m2][(NH)*2+n2], 0, 0, 0); \
            acc[(MH)*4+m2][(NH)*2+n2] = __builtin_amdgcn_mfma_f32_16x16x32_bf16( \
                AR[m2][1], BR[n2][1], acc[(MH)*4+m2][(NH)*2+n2], 0, 0, 0); \
        } \
    } \
    __builtin_amdgcn_s_setprio(0); \
} while (0)

#define BAR()    do { __builtin_amdgcn_s_barrier(); \
                      __builtin_amdgcn_sched_barrier(0); } while (0)
#define LGKM0()  do { asm volatile("s_waitcnt lgkmcnt(0)" ::: "memory"); \
                      __builtin_amdgcn_sched_barrier(0); } while (0)
#define VMCNT(n) do { asm volatile("s_waitcnt vmcnt(" #n ")" ::: "memory"); \
                      __builtin_amdgcn_sched_barrier(0); } while (0)

__global__ __launch_bounds__(512) void gemm_bt256(
    const u16* __restrict__ A, const u16* __restrict__ B, void* __restrict__ Cv,
    int M, int N, int K, int c_is_f32) {
    __shared__ u16 As[32768];   // [dbuf*2+half][128*64]
    __shared__ u16 Bs[32768];
    const int tid = threadIdx.x;
    const int w = tid >> 6, lane = tid & 63;
    const int ln = lane & 15, quad = lane >> 4;
    const int wr = w >> 2, wc = w & 3;

    // XCD-aware bijective chunked swizzle (grid %8 == 0 for both call sites)
    const int gx = gridDim.x;
    const int nwg = gx * gridDim.y;
    const int bid = blockIdx.y * gx + blockIdx.x;
    const int cpx = nwg >> 3;
    const int swz = (bid & 7) * cpx + (bid >> 3);
    const int m0 = (swz / gx) * 256, n0 = (swz % gx) * 256;

    // staging geometry: thread -> (row-in-half = t*64 + w*8 + l3, slot l7),
    // global slot pre-swizzled = l7 ^ l3 (row&7 == l3).
    const int l3 = lane >> 3, l7 = lane & 7;
    const u16* Ast = A + (size_t)(m0 + w * 8 + l3) * K + (l7 ^ l3) * 8;
    const u16* Bst = B + (size_t)(n0 + w * 8 + l3) * K + (l7 ^ l3) * 8;

    auto stageA = [&](int u, int h) {
        const u16* g = Ast + (size_t)(h * 128) * K + u * 64;
        u16* d = As + ((u & 1) * 2 + h) * 8192 + w * 512;
        GLOAD_LDS16(g, d);
        GLOAD_LDS16(g + (size_t)64 * K, d + 4096);
    };
    auto stageB = [&](int u, int h) {
        const u16* g = Bst + (size_t)(h * 128) * K + u * 64;
        u16* d = Bs + ((u & 1) * 2 + h) * 8192 + w * 512;
        GLOAD_LDS16(g, d);
        GLOAD_LDS16(g + (size_t)64 * K, d + 4096);
    };

    // frag-read swizzled column offsets (u16): slot kk*4+quad, XOR row&7 = ln&7
    const int xs0 = ((quad) ^ (ln & 7)) * 8;
    const int xs1 = ((4 + quad) ^ (ln & 7)) * 8;

    bf16x8 a[4][2], b0[2][2], b1[2][2];
    auto loadA = [&](int u, int mh, bf16x8 (&dst)[4][2]) {
        const u16* base = As + ((u & 1) * 2 + wr) * 8192 + (mh * 64 + ln) * 64;
        #pragma unroll
        for (int m2 = 0; m2 < 4; m2++) {
            dst[m2][0] = *(const bf16x8*)(base + m2 * 1024 + xs0);
            dst[m2][1] = *(const bf16x8*)(base + m2 * 1024 + xs1);
        }
    };
    auto loadB = [&](int u, int nh, bf16x8 (&dst)[2][2]) {
        const u16* base = Bs + ((u & 1) * 2 + (wc >> 1)) * 8192
                        + ((wc & 1) * 64 + nh * 32 + ln) * 64;
        #pragma unroll
        for (int n2 = 0; n2 < 2; n2++) {
            dst[n2][0] = *(const bf16x8*)(base + n2 * 1024 + xs0);
            dst[n2][1] = *(const bf16x8*)(base + n2 * 1024 + xs1);
        }
    };

    f32x4 acc[8][4] = {};
    const int NT = K >> 6;

    // prologue: B(0), A(0), B(1); oldest 8 (B0,A0) must land before tile 0 reads
    stageB(0, 0); stageB(0, 1);
    stageA(0, 0); stageA(0, 1);
    stageB(1, 0); stageB(1, 1);
    VMCNT(4);
    BAR();

    for (int u = 0; u < NT; ++u) {
        // ---- P1  (tile-u data guaranteed landed by P4(u-1)'s vmcnt+BAR)
        loadA(u, 0, a);
        loadB(u, 0, b0);
        if (u + 1 < NT) stageA(u + 1, 0);
        BAR(); LGKM0();
        MMAQ(0, 0, a, b0);
        BAR();
        // ---- P2
        loadB(u, 1, b1);
        if (u + 1 < NT) stageA(u + 1, 1);
        BAR(); LGKM0();
        MMAQ(0, 1, a, b1);
        BAR();
        // ---- P3
        loadA(u, 1, a);
        if (u + 2 < NT) stageB(u + 2, 0);
        BAR(); LGKM0();
        MMAQ(1, 1, a, b1);
        BAR();
        // ---- P4
        if (u + 2 < NT) stageB(u + 2, 1);
        BAR();
        MMAQ(1, 0, a, b0);
        // tile-boundary: ensure A(u+1)+B(u+1) landed for ALL waves before the
        // barrier releases anyone into P1(u+1)'s ds_reads.
        if (u + 2 < NT)      { VMCNT(4); }
        else if (u + 1 < NT) { VMCNT(0); }
        BAR();
    }

    #pragma unroll
    for (int mi = 0; mi < 8; mi++)
        #pragma unroll
        for (int ni = 0; ni < 4; ni++)
            #pragma unroll
            for (int r = 0; r < 4; r++) {
                int row = m0 + wr * 128 + mi * 16 + quad * 4 + r;
                int col = n0 + wc * 64 + ni * 16 + ln;
                float v = acc[mi][ni][r];
                if (c_is_f32) ((float*)Cv)[(size_t)row * N + col] = v;
                else          ((u16*)Cv)[(size_t)row * N + col] = f2b(v);
            }
}

// ---------------- Flash attention, GQA, causal, fused paired q-tiles ---------
// (unchanged — at an unexplained ~134.5 µs floor; revisit after GEMMs land)
__global__ __launch_bounds__(512) void attn_kernel(
    const u16* __restrict__ QKV, const u16* __restrict__ VT, u16* __restrict__ O) {
    const int S = 2048, RS = 3072, DO = 2048;
    const int bid = blockIdx.x;                 // 0..511
    const int swz = (bid & 7) * 64 + (bid >> 3);
    const int p = swz & 15, hp = (swz >> 4) & 15, b = swz >> 8;
    const int g = hp >> 1;
    const int qtl = p, qth = 31 - p;            // qtl <= 15 < 16 <= qth
    const int tid = threadIdx.x;
    const int lane = tid & 63, wave = tid >> 6; // wave 0..7
    const int hw = wave >> 2, lw = wave & 3;    // head-half, local wave
    const int h = hp * 2 + hw;
    const int ln = lane & 15, quad = lane >> 4;

    __shared__ u16 Ks[2][64 * 64];              // swizzled, stride 64
    __shared__ u16 Ps[4][64 * 68];
    u16* Psh = &Ps[hw * 2 + 0][0];
    u16* Psl = &Ps[hw * 2 + 1][0];

    const u16* Qb = QKV + (size_t)b * S * RS + h * 64 + quad * 8;
    bf16x8 aqh0 = *(const bf16x8*)(Qb + (size_t)(qth * 64 + lw * 16 + ln) * RS);
    bf16x8 aqh1 = *(const bf16x8*)(Qb + (size_t)(qth * 64 + lw * 16 + ln) * RS + 32);
    bf16x8 aql0 = *(const bf16x8*)(Qb + (size_t)(qtl * 64 + lw * 16 + ln) * RS);
    bf16x8 aql1 = *(const bf16x8*)(Qb + (size_t)(qtl * 64 + lw * 16 + ln) * RS + 32);

    const u16* Kb = QKV + (size_t)b * S * RS + 2048 + g * 64;
    const u16* VTb = VT + (size_t)(b * 8 + g) * 64 * S;

    const bf16x8 vones = {0x3F80, 0x3F80, 0x3F80, 0x3F80, 0x3F80, 0x3F80, 0x3F80, 0x3F80};

    f32x4 acch[5] = {}, accl[5] = {};  // [0..3]=O tiles, [4]=row-sum l

    const int kr = tid >> 3;            // 0..63 (row)
    const int ks = tid & 7;             // 16B slot in row
    const int kswz = ((ks ^ (kr & 7)) * 8);
    bf16x8 kreg;
    bf16x8 vr[2][4];
    auto loadK = [&](int kt) {
        kreg = *(const bf16x8*)(Kb + (size_t)(kt * 64 + kr) * RS + ks * 8);
    };
    auto loadV = [&](int kt) {
        #pragma unroll
        for (int kk = 0; kk < 2; kk++)
            #pragma unroll
            for (int nt = 0; nt < 4; nt++)
                vr[kk][nt] = *(const bf16x8*)(VTb + (size_t)(nt * 16 + ln) * S
                                              + kt * 64 + kk * 32 + quad * 8);
    };

    auto body = [&](int kt, bool DUAL, bool MH, bool ML) {
        u16* KsC = &Ks[kt & 1][0];
        u16* KsN = &Ks[(kt & 1) ^ 1][0];
        if (kt < qth) {
            *(bf16x8*)&KsN[kr * 64 + kswz] = kreg;
        }
        if (kt + 2 <= qth) loadK(kt + 2);

        const int rsw = ln & 7;
        f32x4 sh[4] = {}, sl[4] = {};
        __builtin_amdgcn_s_setprio(1);
        #pragma unroll
        for (int nt = 0; nt < 4; nt++) {
            bf16x8 bk0 = *(const bf16x8*)&KsC[(nt * 16 + ln) * 64 + ((quad ^ rsw) * 8)];
            bf16x8 bk1 = *(const bf16x8*)&KsC[(nt * 16 + ln) * 64 + (((quad + 4) ^ rsw) * 8)];
            sh[nt] = __builtin_amdgcn_mfma_f32_16x16x32_bf16(aqh0, bk0, sh[nt], 0, 0, 0);
            sh[nt] = __builtin_amdgcn_mfma_f32_16x16x32_bf16(aqh1, bk1, sh[nt], 0, 0, 0);
            if (DUAL) {
                sl[nt] = __builtin_amdgcn_mfma_f32_16x16x32_bf16(aql0, bk0, sl[nt], 0, 0, 0);
                sl[nt] = __builtin_amdgcn_mfma_f32_16x16x32_bf16(aql1, bk1, sl[nt], 0, 0, 0);
            }
        }
        __builtin_amdgcn_s_setprio(0);

        if (MH) {
            #pragma unroll
            for (int nt = 0; nt < 4; nt++)
                #pragma unroll
                for (int r = 0; r < 4; r++)
                    if (nt * 16 + ln > lw * 16 + quad * 4 + r) sh[nt][r] = -INFINITY;
        }
        #pragma unroll
        for (int nt = 0; nt < 4; nt++)
            #pragma unroll
            for (int r = 0; r < 4; r++) {
                float pv = exp2f(sh[nt][r]);
                Psh[(lw * 16 + quad * 4 + r) * 68 + nt * 16 + ln] =
                    (u16)(__builtin_bit_cast(unsigned int, pv) >> 16);
            }
        if (DUAL) {
            if (ML) {
                #pragma unroll
                for (int nt = 0; nt < 4; nt++)
                    #pragma unroll
                    for (int r = 0; r < 4; r++)
                        if (nt * 16 + ln > lw * 16 + quad * 4 + r) sl[nt][r] = -INFINITY;
            }
            #pragma unroll
            for (int nt = 0; nt < 4; nt++)
                #pragma unroll
                for (int r = 0; r < 4; r++) {
                    float pv = exp2f(sl[nt][r]);
                    Psl[(lw * 16 + quad * 4 + r) * 68 + nt * 16 + ln] =
                        (u16)(__builtin_bit_cast(unsigned int, pv) >> 16);
                }
        }

        __builtin_amdgcn_s_setprio(1);
        #pragma unroll
        for (int kk = 0; kk < 2; kk++) {
            bf16x8 aph = *(const bf16x8*)&Psh[(lw * 16 + ln) * 68 + kk * 32 + quad * 8];
            #pragma unroll
            for (int nt = 0; nt < 4; nt++)
                acch[nt] = __builtin_amdgcn_mfma_f32_16x16x32_bf16(aph, vr[kk][nt], acch[nt], 0, 0, 0);
            acch[4] = __builtin_amdgcn_mfma_f32_16x16x32_bf16(aph, vones, acch[4], 0, 0, 0);
            if (DUAL) {
                bf16x8 apl = *(const bf16x8*)&Psl[(lw * 16 + ln) * 68 + kk * 32 + quad * 8];
                #pragma unroll
                for (int nt = 0; nt < 4; nt++)
                    accl[nt] = __builtin_amdgcn_mfma_f32_16x16x32_bf16(apl, vr[kk][nt], accl[nt], 0, 0, 0);
                accl[4] = __builtin_amdgcn_mfma_f32_16x16x32_bf16(apl, vones, accl[4], 0, 0, 0);
            }
        }
        __builtin_amdgcn_s_setprio(0);

        if (kt < qth) loadV(kt + 1);
        __syncthreads();
    };

    loadK(0);
    loadV(0);
    *(bf16x8*)&Ks[0][kr * 64 + kswz] = kreg;
    loadK(1);
    __syncthreads();

    for (int kt = 0; kt < qtl; kt++) body(kt, true, false, false);
    body(qtl, true, false, true);
    for (int kt = qtl + 1; kt < qth; kt++) body(kt, false, false, false);
    body(qth, false, true, false);

    u16* Ob = O + (size_t)b * S * DO + h * 64;
    #pragma unroll
    for (int r = 0; r < 4; r++) {
        float invh = 1.0f / acch[4][r];
        float invl = 1.0f / accl[4][r];
        int qh = qth * 64 + lw * 16 + quad * 4 + r;
        int ql = qtl * 64 + lw * 16 + quad * 4 + r;
        #pragma unroll
        for (int nt = 0; nt < 4; nt++) {
            Ob[(size_t)qh * DO + nt * 16 + ln] = f2b(acch[nt][r] * invh);
            Ob[(size_t)ql * DO + nt * 16 + ln] = f2b(accl[nt][r] * invl);
        }
    }
}

extern "C" void kernel_launch(void* const* d_in, const int* in_sizes, int n_in,
                              void* d_out, int out_size, void* d_ws, size_t ws_size,
                              hipStream_t stream) {
    const float* x  = (const float*)d_in[0];
    const float* wq = (const float*)d_in[1];
    const float* wk = (const float*)d_in[2];
    const float* wv = (const float*)d_in[3];
    const float* wo = (const float*)d_in[4];

    const int B = 2, S = 2048, D = 2048;
    const int M = B * S;         // 4096
    const int NQKV = 3072;

    char* ws = (char*)d_ws;
    size_t off = 0;
    auto alloc = [&](size_t bytes) {
        void* p = ws + off;
        off += (bytes + 255) & ~(size_t)255;
        return p;
    };
    u16* xb    = (u16*)alloc((size_t)M * D * 2);        // 16 MB; reused as AO
    u16* wqkvb = (u16*)alloc((size_t)NQKV * D * 2);     // 12 MB; reused as VT
    u16* wob   = (u16*)alloc((size_t)D * D * 2);        // 8 MB
    u16* QKV   = (u16*)alloc((size_t)M * NQKV * 2);     // 24 MB
    u16* AO = xb;      // xb dead after QKV GEMM
    u16* VT = wqkvb;   // wqkvb dead after QKV GEMM

    cast_all<<<dim3(9216), 256, 0, stream>>>(x, wq, wk, wv, wo, xb, wqkvb, wob);

    gemm_bt256<<<dim3(NQKV / 256, M / 256), 512, 0, stream>>>(xb, wqkvb, QKV, M, NQKV, D, 0);

    const float sscale = 0.125f * LOG2E;
    rope_vtrans<<<dim3(5632), 256, 0, stream>>>(QKV, VT, sscale);

    attn_kernel<<<dim3(512), 512, 0, stream>>>(QKV, VT, AO);

    gemm_bt256<<<dim3(D / 256, M / 256), 512, 0, stream>>>(AO, wob, d_out, M, D, D, 1);
}

// Round 6
// 336.294 us; speedup vs baseline: 1.1220x; 1.0881x over previous
//
#include <hip/hip_runtime.h>

typedef unsigned short u16;
typedef __attribute__((ext_vector_type(8))) short bf16x8;
typedef __attribute__((ext_vector_type(4))) float f32x4;

#define LOG2E 1.44269504088896340736f

__device__ inline u16 f2b(float f) {
    unsigned int u = __builtin_bit_cast(unsigned int, f);
    unsigned int r = u + 0x7fffu + ((u >> 16) & 1u);
    return (u16)(r >> 16);
}
__device__ inline float b2f(u16 h) {
    unsigned int u = ((unsigned int)h) << 16;
    return __builtin_bit_cast(float, u);
}

#define GLOAD_LDS16(g, l) \
    __builtin_amdgcn_global_load_lds( \
        (const __attribute__((address_space(1))) unsigned int*)(g), \
        (__attribute__((address_space(3))) unsigned int*)(l), 16, 0, 0)

// ---------------- fused cast fp32 -> bf16 for all 5 inputs, 8 elems/thread ----
__global__ __launch_bounds__(256) void cast_all(
    const float* __restrict__ x, const float* __restrict__ wq,
    const float* __restrict__ wk, const float* __restrict__ wv,
    const float* __restrict__ wo, u16* __restrict__ xb,
    u16* __restrict__ wqkvb, u16* __restrict__ wob) {
    long i = ((long)blockIdx.x * 256 + threadIdx.x) * 8;
    const float* s;
    u16* d;
    if (i < 8388608)       { s = x  + i;              d = xb + i; }
    else if (i < 12582912) { s = wq + (i - 8388608);  d = wqkvb + (i - 8388608); }
    else if (i < 13631488) { s = wk + (i - 12582912); d = wqkvb + 4194304 + (i - 12582912); }
    else if (i < 14680064) { s = wv + (i - 13631488); d = wqkvb + 5242880 + (i - 13631488); }
    else                   { s = wo + (i - 14680064); d = wob + (i - 14680064); }
    float4 v0 = *(const float4*)s;
    float4 v1 = *(const float4*)(s + 4);
    ushort4 o0 = make_ushort4(f2b(v0.x), f2b(v0.y), f2b(v0.z), f2b(v0.w));
    ushort4 o1 = make_ushort4(f2b(v1.x), f2b(v1.y), f2b(v1.z), f2b(v1.w));
    *(ushort4*)d = o0;
    *(ushort4*)(d + 4) = o1;
}

// ---------------- fused RoPE (Q+K) and V-transpose in one launch ----------------
__global__ __launch_bounds__(256) void rope_vtrans(
    u16* __restrict__ qkv, u16* __restrict__ VT, float qscale) {
    const int S = 2048, RS = 3072;
    int tid = threadIdx.x;
    if (blockIdx.x < 5120) {
        int idx = blockIdx.x * 256 + tid;   // < 4096*320
        int row = idx / 320;
        int rem = idx - row * 320;
        int head = rem >> 3, chunk = rem & 7;
        int pos = row & 2047;
        int coloff;
        float scale;
        if (head < 32) { coloff = head * 64;               scale = qscale; }
        else           { coloff = 2048 + (head - 32) * 64; scale = 1.0f; }
        u16* p = qkv + (size_t)row * RS + coloff + chunk * 8;
        bf16x8 v = *(bf16x8*)p;
        float t0 = exp2f((float)(chunk * 4) * -0.41524101186092f);
        const float tc[4] = {1.0f, 0.74989420933246f, 0.56234132519035f, 0.42169650342858f};
        float fpos = (float)pos;
        #pragma unroll
        for (int i = 0; i < 4; i++) {
            float f = fpos * (t0 * tc[i]);
            float rev = f * 0.15915494309189535f;  // radians -> revolutions
            rev = rev - floorf(rev);
            float sn = __builtin_amdgcn_sinf(rev);
            float cs = __builtin_amdgcn_cosf(rev);
            float e0 = b2f((u16)v[2 * i]), e1 = b2f((u16)v[2 * i + 1]);
            v[2 * i]     = (short)f2b((e0 * cs - e1 * sn) * scale);
            v[2 * i + 1] = (short)f2b((e1 * cs + e0 * sn) * scale);
        }
        *(bf16x8*)p = v;
    } else {
        int bid = blockIdx.x - 5120;        // 0..511
        int st = bid & 31, g = (bid >> 5) & 7, b = bid >> 8;
        __shared__ u16 T[64 * 72];
        for (int c = tid; c < 512; c += 256) {
            int sr = c >> 3, dc = (c & 7) * 8;
            *(bf16x8*)&T[sr * 72 + dc] =
                *(const bf16x8*)(qkv + ((size_t)b * S + st * 64 + sr) * RS + 2560 + g * 64 + dc);
        }
        __syncthreads();
        for (int c = tid; c < 512; c += 256) {
            int d = c >> 3, sc = (c & 7) * 8;
            bf16x8 o;
            #pragma unroll
            for (int j = 0; j < 8; j++) o[j] = (short)T[(sc + j) * 72 + d];
            *(bf16x8*)(VT + ((size_t)((b * 8 + g) * 64 + d)) * S + st * 64 + sc) = o;
        }
    }
}

// ---------------- GEMM 256x256 8-phase (m201-style port): C[M,N]=A[M,K]*B[N,K]^T
// (unchanged from round 4/5 — no counter visibility yet; revisit once attn drops
// below GEMM dispatch time and they appear in the top-5.)
#define MMAQ(MH, NH, AR, BR) do { \
    __builtin_amdgcn_s_setprio(1); \
    _Pragma("unroll") \
    for (int m2 = 0; m2 < 4; m2++) { \
        _Pragma("unroll") \
        for (int n2 = 0; n2 < 2; n2++) { \
            acc[(MH)*4+m2][(NH)*2+n2] = __builtin_amdgcn_mfma_f32_16x16x32_bf16( \
                AR[m2][0], BR[n2][0], acc[(MH)*4+m2][(NH)*2+n2], 0, 0, 0); \
            acc[(MH)*4+m2][(NH)*2+n2] = __builtin_amdgcn_mfma_f32_16x16x32_bf16( \
                AR[m2][1], BR[n2][1], acc[(MH)*4+m2][(NH)*2+n2], 0, 0, 0); \
        } \
    } \
    __builtin_amdgcn_s_setprio(0); \
} while (0)

#define BAR()    do { __builtin_amdgcn_s_barrier(); \
                      __builtin_amdgcn_sched_barrier(0); } while (0)
#define LGKM0()  do { asm volatile("s_waitcnt lgkmcnt(0)" ::: "memory"); \
                      __builtin_amdgcn_sched_barrier(0); } while (0)
#define VMCNT(n) do { asm volatile("s_waitcnt vmcnt(" #n ")" ::: "memory"); \
                      __builtin_amdgcn_sched_barrier(0); } while (0)

__global__ __launch_bounds__(512) void gemm_bt256(
    const u16* __restrict__ A, const u16* __restrict__ B, void* __restrict__ Cv,
    int M, int N, int K, int c_is_f32) {
    __shared__ u16 As[32768];   // [dbuf*2+half][128*64]
    __shared__ u16 Bs[32768];
    const int tid = threadIdx.x;
    const int w = tid >> 6, lane = tid & 63;
    const int ln = lane & 15, quad = lane >> 4;
    const int wr = w >> 2, wc = w & 3;

    const int gx = gridDim.x;
    const int nwg = gx * gridDim.y;
    const int bid = blockIdx.y * gx + blockIdx.x;
    const int cpx = nwg >> 3;
    const int swz = (bid & 7) * cpx + (bid >> 3);
    const int m0 = (swz / gx) * 256, n0 = (swz % gx) * 256;

    const int l3 = lane >> 3, l7 = lane & 7;
    const u16* Ast = A + (size_t)(m0 + w * 8 + l3) * K + (l7 ^ l3) * 8;
    const u16* Bst = B + (size_t)(n0 + w * 8 + l3) * K + (l7 ^ l3) * 8;

    auto stageA = [&](int u, int h) {
        const u16* g = Ast + (size_t)(h * 128) * K + u * 64;
        u16* d = As + ((u & 1) * 2 + h) * 8192 + w * 512;
        GLOAD_LDS16(g, d);
        GLOAD_LDS16(g + (size_t)64 * K, d + 4096);
    };
    auto stageB = [&](int u, int h) {
        const u16* g = Bst + (size_t)(h * 128) * K + u * 64;
        u16* d = Bs + ((u & 1) * 2 + h) * 8192 + w * 512;
        GLOAD_LDS16(g, d);
        GLOAD_LDS16(g + (size_t)64 * K, d + 4096);
    };

    const int xs0 = ((quad) ^ (ln & 7)) * 8;
    const int xs1 = ((4 + quad) ^ (ln & 7)) * 8;

    bf16x8 a[4][2], b0[2][2], b1[2][2];
    auto loadA = [&](int u, int mh, bf16x8 (&dst)[4][2]) {
        const u16* base = As + ((u & 1) * 2 + wr) * 8192 + (mh * 64 + ln) * 64;
        #pragma unroll
        for (int m2 = 0; m2 < 4; m2++) {
            dst[m2][0] = *(const bf16x8*)(base + m2 * 1024 + xs0);
            dst[m2][1] = *(const bf16x8*)(base + m2 * 1024 + xs1);
        }
    };
    auto loadB = [&](int u, int nh, bf16x8 (&dst)[2][2]) {
        const u16* base = Bs + ((u & 1) * 2 + (wc >> 1)) * 8192
                        + ((wc & 1) * 64 + nh * 32 + ln) * 64;
        #pragma unroll
        for (int n2 = 0; n2 < 2; n2++) {
            dst[n2][0] = *(const bf16x8*)(base + n2 * 1024 + xs0);
            dst[n2][1] = *(const bf16x8*)(base + n2 * 1024 + xs1);
        }
    };

    f32x4 acc[8][4] = {};
    const int NT = K >> 6;

    stageB(0, 0); stageB(0, 1);
    stageA(0, 0); stageA(0, 1);
    stageB(1, 0); stageB(1, 1);
    VMCNT(4);
    BAR();

    for (int u = 0; u < NT; ++u) {
        // ---- P1
        loadA(u, 0, a);
        loadB(u, 0, b0);
        if (u + 1 < NT) stageA(u + 1, 0);
        BAR(); LGKM0();
        MMAQ(0, 0, a, b0);
        BAR();
        // ---- P2
        loadB(u, 1, b1);
        if (u + 1 < NT) stageA(u + 1, 1);
        BAR(); LGKM0();
        MMAQ(0, 1, a, b1);
        BAR();
        // ---- P3
        loadA(u, 1, a);
        if (u + 2 < NT) stageB(u + 2, 0);
        BAR(); LGKM0();
        MMAQ(1, 1, a, b1);
        BAR();
        // ---- P4
        if (u + 2 < NT) stageB(u + 2, 1);
        BAR();
        MMAQ(1, 0, a, b0);
        if (u + 2 < NT)      { VMCNT(4); }
        else if (u + 1 < NT) { VMCNT(0); }
        BAR();
    }

    #pragma unroll
    for (int mi = 0; mi < 8; mi++)
        #pragma unroll
        for (int ni = 0; ni < 4; ni++)
            #pragma unroll
            for (int r = 0; r < 4; r++) {
                int row = m0 + wr * 128 + mi * 16 + quad * 4 + r;
                int col = n0 + wc * 64 + ni * 16 + ln;
                float v = acc[mi][ni][r];
                if (c_is_f32) ((float*)Cv)[(size_t)row * N + col] = v;
                else          ((u16*)Cv)[(size_t)row * N + col] = f2b(v);
            }
}

// ---------------- Flash attention, GQA, causal, fused paired q-tiles ---------
// ROUND-5 CHANGE: V re-staged in LDS (double-buffered, same XOR swizzle as K).
// Cycle model that closes attn's 320K cyc/CU: V-fragment reads were ~130K cyc
// (8 waves x 8KB redundant global reads of the same 8KB tile per block-body =
// 64KB/body through L1/L2 at ~32-64 B/cyc vs LDS 85-128 B/cyc). Staging V once
// per block (8KB reg->ds_write) and reading fragments via ds_read_b128 cuts
// that term 2-4x. bv is reused across the dual h/l MFMA pair. Side effect: the
// staged loads are issued a full body before the barrier that drains them.
__global__ __launch_bounds__(512) void attn_kernel(
    const u16* __restrict__ QKV, const u16* __restrict__ VT, u16* __restrict__ O) {
    const int S = 2048, RS = 3072, DO = 2048;
    const int bid = blockIdx.x;                 // 0..511
    const int swz = (bid & 7) * 64 + (bid >> 3);
    const int p = swz & 15, hp = (swz >> 4) & 15, b = swz >> 8;
    const int g = hp >> 1;
    const int qtl = p, qth = 31 - p;            // qtl <= 15 < 16 <= qth
    const int tid = threadIdx.x;
    const int lane = tid & 63, wave = tid >> 6; // wave 0..7
    const int hw = wave >> 2, lw = wave & 3;    // head-half, local wave
    const int h = hp * 2 + hw;
    const int ln = lane & 15, quad = lane >> 4;

    __shared__ u16 Ks[2][64 * 64];              // swizzled, stride 64
    __shared__ u16 Vs[2][64 * 64];              // swizzled, stride 64
    __shared__ u16 Ps[4][64 * 68];
    u16* Psh = &Ps[hw * 2 + 0][0];
    u16* Psl = &Ps[hw * 2 + 1][0];

    const u16* Qb = QKV + (size_t)b * S * RS + h * 64 + quad * 8;
    bf16x8 aqh0 = *(const bf16x8*)(Qb + (size_t)(qth * 64 + lw * 16 + ln) * RS);
    bf16x8 aqh1 = *(const bf16x8*)(Qb + (size_t)(qth * 64 + lw * 16 + ln) * RS + 32);
    bf16x8 aql0 = *(const bf16x8*)(Qb + (size_t)(qtl * 64 + lw * 16 + ln) * RS);
    bf16x8 aql1 = *(const bf16x8*)(Qb + (size_t)(qtl * 64 + lw * 16 + ln) * RS + 32);

    const u16* Kb = QKV + (size_t)b * S * RS + 2048 + g * 64;
    const u16* VTb = VT + (size_t)(b * 8 + g) * 64 * S;

    const bf16x8 vones = {0x3F80, 0x3F80, 0x3F80, 0x3F80, 0x3F80, 0x3F80, 0x3F80, 0x3F80};

    f32x4 acch[5] = {}, accl[5] = {};  // [0..3]=O tiles, [4]=row-sum l

    // K/V staging: each of 512 threads owns one 16B chunk of each 64x64 tile.
    const int kr = tid >> 3;            // 0..63 (row; K: k-row, V: d-row)
    const int ks = tid & 7;             // 16B slot in row
    const int kswz = ((ks ^ (kr & 7)) * 8);
    bf16x8 kreg, vreg;
    auto loadKV = [&](int kt) {
        kreg = *(const bf16x8*)(Kb + (size_t)(kt * 64 + kr) * RS + ks * 8);
        vreg = *(const bf16x8*)(VTb + (size_t)kr * S + kt * 64 + ks * 8);
    };

    // body invariants at entry: Ks/Vs[kt&1] hold tile kt; kreg/vreg hold
    // tile kt+1 (if any).
    auto body = [&](int kt, bool DUAL, bool MH, bool ML) {
        u16* KsC = &Ks[kt & 1][0];
        u16* VsC = &Vs[kt & 1][0];
        if (kt < qth) {   // stage NEXT tile; readers finished last body
            u16* KsN = &Ks[(kt & 1) ^ 1][0];
            u16* VsN = &Vs[(kt & 1) ^ 1][0];
            *(bf16x8*)&KsN[kr * 64 + kswz] = kreg;
            *(bf16x8*)&VsN[kr * 64 + kswz] = vreg;
        }
        if (kt + 2 <= qth) loadKV(kt + 2);

        const int rsw = ln & 7;
        f32x4 sh[4] = {}, sl[4] = {};
        __builtin_amdgcn_s_setprio(1);
        #pragma unroll
        for (int nt = 0; nt < 4; nt++) {
            bf16x8 bk0 = *(const bf16x8*)&KsC[(nt * 16 + ln) * 64 + ((quad ^ rsw) * 8)];
            bf16x8 bk1 = *(const bf16x8*)&KsC[(nt * 16 + ln) * 64 + (((quad + 4) ^ rsw) * 8)];
            sh[nt] = __builtin_amdgcn_mfma_f32_16x16x32_bf16(aqh0, bk0, sh[nt], 0, 0, 0);
            sh[nt] = __builtin_amdgcn_mfma_f32_16x16x32_bf16(aqh1, bk1, sh[nt], 0, 0, 0);
            if (DUAL) {
                sl[nt] = __builtin_amdgcn_mfma_f32_16x16x32_bf16(aql0, bk0, sl[nt], 0, 0, 0);
                sl[nt] = __builtin_amdgcn_mfma_f32_16x16x32_bf16(aql1, bk1, sl[nt], 0, 0, 0);
            }
        }
        __builtin_amdgcn_s_setprio(0);

        if (MH) {
            #pragma unroll
            for (int nt = 0; nt < 4; nt++)
                #pragma unroll
                for (int r = 0; r < 4; r++)
                    if (nt * 16 + ln > lw * 16 + quad * 4 + r) sh[nt][r] = -INFINITY;
        }
        #pragma unroll
        for (int nt = 0; nt < 4; nt++)
            #pragma unroll
            for (int r = 0; r < 4; r++) {
                float pv = exp2f(sh[nt][r]);
                Psh[(lw * 16 + quad * 4 + r) * 68 + nt * 16 + ln] =
                    (u16)(__builtin_bit_cast(unsigned int, pv) >> 16);
            }
        if (DUAL) {
            if (ML) {
                #pragma unroll
                for (int nt = 0; nt < 4; nt++)
                    #pragma unroll
                    for (int r = 0; r < 4; r++)
                        if (nt * 16 + ln > lw * 16 + quad * 4 + r) sl[nt][r] = -INFINITY;
            }
            #pragma unroll
            for (int nt = 0; nt < 4; nt++)
                #pragma unroll
                for (int r = 0; r < 4; r++) {
                    float pv = exp2f(sl[nt][r]);
                    Psl[(lw * 16 + quad * 4 + r) * 68 + nt * 16 + ln] =
                        (u16)(__builtin_bit_cast(unsigned int, pv) >> 16);
                }
        }
        // no barrier: Ps rows are wave-private (same-wave LDS ordering)

        __builtin_amdgcn_s_setprio(1);
        #pragma unroll
        for (int kk = 0; kk < 2; kk++) {
            bf16x8 aph = *(const bf16x8*)&Psh[(lw * 16 + ln) * 68 + kk * 32 + quad * 8];
            bf16x8 apl;
            if (DUAL) apl = *(const bf16x8*)&Psl[(lw * 16 + ln) * 68 + kk * 32 + quad * 8];
            #pragma unroll
            for (int nt = 0; nt < 4; nt++) {
                bf16x8 bv = *(const bf16x8*)&VsC[(nt * 16 + ln) * 64
                                                 + (((kk * 4 + quad) ^ rsw) * 8)];
                acch[nt] = __builtin_amdgcn_mfma_f32_16x16x32_bf16(aph, bv, acch[nt], 0, 0, 0);
                if (DUAL)
                    accl[nt] = __builtin_amdgcn_mfma_f32_16x16x32_bf16(apl, bv, accl[nt], 0, 0, 0);
            }
            acch[4] = __builtin_amdgcn_mfma_f32_16x16x32_bf16(aph, vones, acch[4], 0, 0, 0);
            if (DUAL)
                accl[4] = __builtin_amdgcn_mfma_f32_16x16x32_bf16(apl, vones, accl[4], 0, 0, 0);
        }
        __builtin_amdgcn_s_setprio(0);

        __syncthreads();               // single barrier per body
    };

    // prologue: stage tile 0 into buf 0, prefetch tile 1 into regs.
    loadKV(0);
    *(bf16x8*)&Ks[0][kr * 64 + kswz] = kreg;
    *(bf16x8*)&Vs[0][kr * 64 + kswz] = vreg;
    loadKV(1);
    __syncthreads();

    for (int kt = 0; kt < qtl; kt++) body(kt, true, false, false);
    body(qtl, true, false, true);
    for (int kt = qtl + 1; kt < qth; kt++) body(kt, false, false, false);
    body(qth, false, true, false);

    // epilogue
    u16* Ob = O + (size_t)b * S * DO + h * 64;
    #pragma unroll
    for (int r = 0; r < 4; r++) {
        float invh = 1.0f / acch[4][r];
        float invl = 1.0f / accl[4][r];
        int qh = qth * 64 + lw * 16 + quad * 4 + r;
        int ql = qtl * 64 + lw * 16 + quad * 4 + r;
        #pragma unroll
        for (int nt = 0; nt < 4; nt++) {
            Ob[(size_t)qh * DO + nt * 16 + ln] = f2b(acch[nt][r] * invh);
            Ob[(size_t)ql * DO + nt * 16 + ln] = f2b(accl[nt][r] * invl);
        }
    }
}

extern "C" void kernel_launch(void* const* d_in, const int* in_sizes, int n_in,
                              void* d_out, int out_size, void* d_ws, size_t ws_size,
                              hipStream_t stream) {
    const float* x  = (const float*)d_in[0];
    const float* wq = (const float*)d_in[1];
    const float* wk = (const float*)d_in[2];
    const float* wv = (const float*)d_in[3];
    const float* wo = (const float*)d_in[4];

    const int B = 2, S = 2048, D = 2048;
    const int M = B * S;         // 4096
    const int NQKV = 3072;

    char* ws = (char*)d_ws;
    size_t off = 0;
    auto alloc = [&](size_t bytes) {
        void* p = ws + off;
        off += (bytes + 255) & ~(size_t)255;
        return p;
    };
    u16* xb    = (u16*)alloc((size_t)M * D * 2);        // 16 MB; reused as AO
    u16* wqkvb = (u16*)alloc((size_t)NQKV * D * 2);     // 12 MB; reused as VT
    u16* wob   = (u16*)alloc((size_t)D * D * 2);        // 8 MB
    u16* QKV   = (u16*)alloc((size_t)M * NQKV * 2);     // 24 MB
    u16* AO = xb;      // xb dead after QKV GEMM
    u16* VT = wqkvb;   // wqkvb dead after QKV GEMM

    cast_all<<<dim3(9216), 256, 0, stream>>>(x, wq, wk, wv, wo, xb, wqkvb, wob);

    gemm_bt256<<<dim3(NQKV / 256, M / 256), 512, 0, stream>>>(xb, wqkvb, QKV, M, NQKV, D, 0);

    const float sscale = 0.125f * LOG2E;
    rope_vtrans<<<dim3(5632), 256, 0, stream>>>(QKV, VT, sscale);

    attn_kernel<<<dim3(512), 512, 0, stream>>>(QKV, VT, AO);

    gemm_bt256<<<dim3(D / 256, M / 256), 512, 0, stream>>>(AO, wob, d_out, M, D, D, 1);
}